// Round 8
// baseline (791.201 us; speedup 1.0000x reference)
//
#include <hip/hip_runtime.h>
#include <cstdint>
#include <cstddef>

#define NN 50000
#define NE 800000

typedef _Float16 f16x8 __attribute__((ext_vector_type(8)));
typedef _Float16 f16x4 __attribute__((ext_vector_type(4)));
typedef float f32x4 __attribute__((ext_vector_type(4)));

// ---------------------------------------------------------------------------
// Edge-index dtype robustness (int64 vs int32 canonicalization)
// ---------------------------------------------------------------------------
__device__ __forceinline__ int edge_at(const void* e, int is32, long long i) {
    return is32 ? ((const int*)e)[i] : (int)((const long long*)e)[i];
}

__global__ __launch_bounds__(64) void zero_flag_k(int* flag) {
    if (threadIdx.x == 0) *flag = 0;
}

__global__ __launch_bounds__(256) void detect_k(const int* __restrict__ w, int* __restrict__ flag) {
    int i = blockIdx.x * 256 + threadIdx.x;   // 0..1023
    if (i < 1024 && w[2 * i + 1] != 0) atomicOr(flag, 1);
}

// ---------------------------------------------------------------------------
// Hadamard: X0 = qe*obj, fp16 hi/lo split, written SLICE-MAJOR:
// X[panel][node][32], panel = col>>5.
// ---------------------------------------------------------------------------
__global__ __launch_bounds__(256) void hadamard_k(const float4* __restrict__ a,
                                                  const float4* __restrict__ b,
                                                  _Float16* __restrict__ Xh,
                                                  _Float16* __restrict__ Xl, int n4) {
    int i = blockIdx.x * 256 + threadIdx.x;
    if (i >= n4) return;
    float4 x = a[i], y = b[i];
    float v[4] = { x.x * y.x, x.y * y.y, x.z * y.z, x.w * y.w };
    f16x4 hh, ll;
    #pragma unroll
    for (int j = 0; j < 4; ++j) {
        _Float16 h = (_Float16)v[j];
        hh[j] = h;
        ll[j] = (_Float16)(v[j] - (float)h);
    }
    int row = i >> 6;              // 64 float4 per 256-col row
    int cq  = (i & 63) * 4;        // col base
    size_t off = ((size_t)(cq >> 5) * NN + row) * 32 + (cq & 31);
    *(f16x4*)&Xh[off] = hh;
    *(f16x4*)&Xl[off] = ll;
}

// ---------------------------------------------------------------------------
// Degree / CSR build
// ---------------------------------------------------------------------------
__global__ __launch_bounds__(256) void init_k(int* __restrict__ deg, int* __restrict__ cursor, int n) {
    int i = blockIdx.x * 256 + threadIdx.x;
    if (i < n) { deg[i] = 1; cursor[i] = 0; }   // self-loop
}

__global__ __launch_bounds__(256) void count_k(const void* __restrict__ edges,
                                               const int* __restrict__ flag,
                                               int* __restrict__ deg, int e) {
    int i = blockIdx.x * 256 + threadIdx.x;
    if (i < e) {
        int is32 = *flag;
        atomicAdd(&deg[edge_at(edges, is32, i)], 1);
    }
}

__global__ __launch_bounds__(256) void dinv_k(const int* __restrict__ deg, float* __restrict__ dinv, int n) {
    int i = blockIdx.x * 256 + threadIdx.x;
    if (i < n) dinv[i] = rsqrtf((float)deg[i]);
}

__global__ __launch_bounds__(1024) void scan_k(const int* __restrict__ deg, int* __restrict__ rp, int n) {
    __shared__ int s[1024];
    int t = threadIdx.x;
    int chunk = (n + 1023) / 1024;
    int lo = t * chunk;
    int hi = lo + chunk; if (hi > n) hi = n;
    int sum = 0;
    for (int i = lo; i < hi; ++i) sum += deg[i] - 1;
    s[t] = sum;
    __syncthreads();
    for (int off = 1; off < 1024; off <<= 1) {
        int val = (t >= off) ? s[t - off] : 0;
        __syncthreads();
        s[t] += val;
        __syncthreads();
    }
    int run = (t == 0) ? 0 : s[t - 1];
    for (int i = lo; i < hi; ++i) { rp[i] = run; run += deg[i] - 1; }
    if (t == 1023) rp[n] = s[1023];
}

__global__ __launch_bounds__(256) void scatter_k(const void* __restrict__ edges,
                                                 const int* __restrict__ flag,
                                                 const int* __restrict__ rp,
                                                 int* __restrict__ cursor,
                                                 int* __restrict__ col_s, int e) {
    int i = blockIdx.x * 256 + threadIdx.x;
    if (i < e) {
        int is32 = *flag;
        int r = edge_at(edges, is32, i);
        int c = edge_at(edges, is32, (long long)NE + i);
        int pos = rp[r] + atomicAdd(&cursor[r], 1);
        col_s[pos] = c;
    }
}

// ---------------------------------------------------------------------------
// Degree-sorted node permutation (counting sort, 1024 buckets).
// Waves then process ~equal-degree nodes: max-degree divergence ~= 1.
// Bucket order is atomics-nondeterministic but per-node arithmetic is
// unchanged, so outputs are identical.
// ---------------------------------------------------------------------------
__global__ __launch_bounds__(1024) void hzero_k(int* __restrict__ hist) {
    hist[threadIdx.x] = 0;
}

__global__ __launch_bounds__(256) void hist_k(const int* __restrict__ deg,
                                              int* __restrict__ hist, int n) {
    int i = blockIdx.x * 256 + threadIdx.x;
    if (i < n) atomicAdd(&hist[min(deg[i], 1023)], 1);
}

__global__ __launch_bounds__(1024) void hscan_k(const int* __restrict__ hist,
                                                int* __restrict__ bcur) {
    __shared__ int s[1024];
    int t = threadIdx.x;
    s[t] = hist[t];
    __syncthreads();
    for (int off = 1; off < 1024; off <<= 1) {
        int val = (t >= off) ? s[t - off] : 0;
        __syncthreads();
        s[t] += val;
        __syncthreads();
    }
    bcur[t] = (t == 0) ? 0 : s[t - 1];
}

__global__ __launch_bounds__(256) void pscatter_k(const int* __restrict__ deg,
                                                  int* __restrict__ bcur,
                                                  int* __restrict__ perm, int n) {
    int i = blockIdx.x * 256 + threadIdx.x;
    if (i < n) {
        int b = min(deg[i], 1023);
        int pos = atomicAdd(&bcur[b], 1);
        perm[pos] = i;
    }
}

// ---------------------------------------------------------------------------
// W convert: W[K=256][Nout] fp32 -> B3 [Nout][768] fp16, layout [Wh | Wl | Wh]
// ---------------------------------------------------------------------------
__global__ __launch_bounds__(256) void wconv3_k(const float* __restrict__ W,
                                                _Float16* __restrict__ B3, int Nout) {
    int n = blockIdx.x;            // 0..Nout-1
    int k = threadIdx.x;           // 0..255
    float v = W[(size_t)k * Nout + n];
    _Float16 h = (_Float16)v;
    _Float16 l = (_Float16)(v - (float)h);
    B3[(size_t)n * 768 + k]       = h;
    B3[(size_t)n * 768 + 256 + k] = l;
    B3[(size_t)n * 768 + 512 + k] = h;
}

// ---------------------------------------------------------------------------
// fp16 MFMA GEMM over virtual K=768, slice-major A & C.
// Epilogue writes G = dinv[row] * (A@W)  (pre-scaled for the gather step).
// ---------------------------------------------------------------------------
__device__ __forceinline__ void gload_lds16(const void* g, void* l) {
    __builtin_amdgcn_global_load_lds(
        (const __attribute__((address_space(1))) void*)g,
        (__attribute__((address_space(3))) void*)l, 16, 0, 0);
}

template <int NBX, int SW>
__global__ __launch_bounds__(256) void gemm_f16_k(const _Float16* __restrict__ Ah,
                                                  const _Float16* __restrict__ Al,
                                                  const _Float16* __restrict__ B3,
                                                  const float* __restrict__ dinv,
                                                  _Float16* __restrict__ C,
                                                  int M, int Nout) {
    __shared__ alignas(16) _Float16 sA[128 * 32];   // linear: row r at r*32, 64B rows
    __shared__ alignas(16) _Float16 sB[128 * 32];
    constexpr int LG = (SW == 32) ? 5 : 4;
    int mblk = (M + 127) >> 7;

    int pair, xb;
    if (NBX == 2) {
        int b = blockIdx.x;
        pair = (b >> 4) * 8 + (b & 7);     // row-panel id; pinned to XCD (b&7)
        xb   = (b >> 3) & 1;
        if (pair >= mblk) return;
    } else {
        pair = blockIdx.x;
        xb = 0;
    }

    int tid = threadIdx.x;
    int row0 = pair * 128, col0 = xb * 128;
    int wid = tid >> 6, lane = tid & 63;
    int wm = wid >> 1, wn = wid & 1;
    int fr = lane & 15;
    int kb = (lane >> 4) * 8;       // k element base within 32

    int sr = lane >> 2;
    int ke = (lane & 3) * 8;

    f32x4 acc[4][4] = {};

    for (int s = 0; s < 24; ++s) {
        int seg = s >> 3;                 // 0: Ah, 1: Ah (L2-hot), 2: Al
        int p = s & 7;                    // A k-panel index
        const _Float16* Asrc = (seg == 2) ? Al : Ah;

        __syncthreads();                  // LDS reuse: prior reads done
        #pragma unroll
        for (int c = 0; c < 2; ++c) {
            int ch = wid * 2 + c;         // 0..7
            int r = ch * 16 + sr;
            int arow = row0 + r;
            if (arow < M)
                gload_lds16(&Asrc[((size_t)p * M + arow) * 32 + ke], &sA[ch * 512]);
            gload_lds16(&B3[(size_t)(col0 + r) * 768 + s * 32 + ke], &sB[ch * 512]);
        }
        __syncthreads();                  // drains vmcnt (global_load_lds) too

        f16x8 af[4];
        #pragma unroll
        for (int f = 0; f < 4; ++f)
            af[f] = *(const f16x8*)&sA[(wm * 64 + f * 16 + fr) * 32 + kb];
        #pragma unroll
        for (int g = 0; g < 4; ++g) {
            f16x8 bf_ = *(const f16x8*)&sB[(wn * 64 + g * 16 + fr) * 32 + kb];
            #pragma unroll
            for (int f = 0; f < 4; ++f)
                acc[f][g] = __builtin_amdgcn_mfma_f32_16x16x32_f16(af[f], bf_, acc[f][g], 0, 0, 0);
        }
    }

    int rsub = (lane >> 4) * 4;
    float dsc[4][4];
    #pragma unroll
    for (int f = 0; f < 4; ++f)
        #pragma unroll
        for (int r = 0; r < 4; ++r) {
            int row = row0 + wm * 64 + f * 16 + rsub + r;
            dsc[f][r] = (row < M) ? dinv[row] : 0.0f;
        }
    #pragma unroll
    for (int f = 0; f < 4; ++f) {
        #pragma unroll
        for (int g = 0; g < 4; ++g) {
            int col = col0 + wn * 64 + g * 16 + fr;
            #pragma unroll
            for (int r = 0; r < 4; ++r) {
                int row = row0 + wm * 64 + f * 16 + rsub + r;
                if (row < M)
                    C[((size_t)(col >> LG) * M + row) * SW + (col & (SW - 1))] =
                        (_Float16)(acc[f][g][r] * dsc[f][r]);
            }
        }
    }
}

// ---------------------------------------------------------------------------
// XCD-sliced aggregation v6: gathers pre-scaled G = diag(dinv)*H (slice-major
// fp16). out[v] = dinv[v]*(G[v] + sum_edges G[c]) + b -- per edge: ONE gather,
// one add chain (no dinv lookup, no multiply). Nodes processed in degree-
// sorted order via perm -> wave max-degree ~= mean (no divergence waste).
// MODE 0: relu, slice-major fp16 hi/lo out. MODE 1: fp32 row-major out.
// ---------------------------------------------------------------------------
template <int D, int MODE>
__global__ __launch_bounds__(256) void aggregate_slice_k(const _Float16* __restrict__ G,
                                                         const float* __restrict__ bias,
                                                         const float* __restrict__ dinv,
                                                         const int* __restrict__ rp,
                                                         const int* __restrict__ cs,
                                                         const int* __restrict__ perm,
                                                         _Float16* __restrict__ Yh,
                                                         _Float16* __restrict__ Yl,
                                                         float* __restrict__ Yf, int n) {
    constexpr int SLICE = (D == 256) ? 32 : 16;   // panel width
    constexpr int LPN = SLICE / 8;                // lanes per node (f16x8 each)
    constexpr int NPB = 256 / LPN;                // nodes per block

    int bid = blockIdx.x;
    int s = bid & 7;
    int slot = (bid >> 3) * NPB + threadIdx.x / LPN;
    if (slot >= n) return;
    int v = perm[slot];
    int sub = threadIdx.x % LPN;
    int co = sub * 8;                             // within-panel col offset
    int col = s * SLICE + co;                     // global col (bias / out)

    const _Float16* Gs = G + (size_t)s * n * SLICE;   // this slice's panel

    float acc[8];
    {
        f16x8 t0 = *(const f16x8*)&Gs[(size_t)v * SLICE + co];
        #pragma unroll
        for (int i = 0; i < 8; ++i) acc[i] = (float)t0[i];
    }

    int beg = rp[v], end = rp[v + 1];
    int j = beg;
    for (; j + 8 <= end; j += 8) {
        int cc[8];
        #pragma unroll
        for (int u = 0; u < 8; ++u) cc[u] = cs[j + u];
        f16x8 hv[8];
        #pragma unroll
        for (int u = 0; u < 8; ++u)
            hv[u] = *(const f16x8*)&Gs[(size_t)cc[u] * SLICE + co];
        #pragma unroll
        for (int u = 0; u < 8; ++u)
            #pragma unroll
            for (int i = 0; i < 8; ++i)
                acc[i] += (float)hv[u][i];
    }
    for (; j < end; ++j) {
        int c = cs[j];
        f16x8 a = *(const f16x8*)&Gs[(size_t)c * SLICE + co];
        #pragma unroll
        for (int i = 0; i < 8; ++i) acc[i] += (float)a[i];
    }

    float dv = dinv[v];
    float4 b0 = *(const float4*)&bias[col];
    float4 b1 = *(const float4*)&bias[col + 4];
    float bb[8] = { b0.x, b0.y, b0.z, b0.w, b1.x, b1.y, b1.z, b1.w };

    if constexpr (MODE == 0) {
        f16x8 hh, ll;
        #pragma unroll
        for (int i = 0; i < 8; ++i) {
            float o = fmaxf(dv * acc[i] + bb[i], 0.0f);
            _Float16 h = (_Float16)o;
            hh[i] = h;
            ll[i] = (_Float16)(o - (float)h);
        }
        size_t off = ((size_t)s * n + v) * SLICE + co;   // slice-major out
        *(f16x8*)&Yh[off] = hh;
        *(f16x8*)&Yl[off] = ll;
    } else {
        float o[8];
        #pragma unroll
        for (int i = 0; i < 8; ++i) o[i] = dv * acc[i] + bb[i];
        *(float4*)&Yf[(size_t)v * D + col]     = make_float4(o[0], o[1], o[2], o[3]);
        *(float4*)&Yf[(size_t)v * D + col + 4] = make_float4(o[4], o[5], o[6], o[7]);
    }
}

// ---------------------------------------------------------------------------
extern "C" void kernel_launch(void* const* d_in, const int* in_sizes, int n_in,
                              void* d_out, int out_size, void* d_ws, size_t ws_size,
                              hipStream_t stream) {
    const float* qe  = (const float*)d_in[0];
    const float* obj = (const float*)d_in[1];
    const void*  edges = d_in[2];
    const float* W1 = (const float*)d_in[3];
    const float* b1 = (const float*)d_in[4];
    const float* W2 = (const float*)d_in[5];
    const float* b2 = (const float*)d_in[6];
    const float* W3 = (const float*)d_in[7];
    const float* b3 = (const float*)d_in[8];
    float* out = (float*)d_out;

    char* p = (char*)d_ws;
    _Float16* Xh   = (_Float16*)p; p += (size_t)NN * 256 * 2;   // 25.6 MB (slice-major)
    _Float16* Xl   = (_Float16*)p; p += (size_t)NN * 256 * 2;   // 25.6 MB (slice-major)
    _Float16* H    = (_Float16*)p; p += (size_t)NN * 256 * 2;   // 25.6 MB (slice-major, pre-scaled G)
    _Float16* B3   = (_Float16*)p; p += (size_t)256 * 768 * 2;  // 0.4 MB
    int*   deg     = (int*)p;   p += (size_t)NN * 4;
    float* dinv    = (float*)p; p += (size_t)NN * 4;
    int*   rp      = (int*)p;   p += (size_t)(NN + 1) * 4;
    int*   cursor  = (int*)p;   p += (size_t)NN * 4;
    int*   col_s   = (int*)p;   p += (size_t)NE * 4;
    int*   hist    = (int*)p;   p += 1024 * 4;
    int*   bcur    = (int*)p;   p += 1024 * 4;
    int*   perm    = (int*)p;   p += (size_t)NN * 4;
    int*   flag    = (int*)p;   p += 4;

    zero_flag_k<<<1, 64, 0, stream>>>(flag);
    detect_k<<<4, 256, 0, stream>>>((const int*)edges, flag);
    hadamard_k<<<(NN * 64 + 255) / 256, 256, 0, stream>>>(
        (const float4*)qe, (const float4*)obj, Xh, Xl, NN * 64);
    init_k<<<(NN + 255) / 256, 256, 0, stream>>>(deg, cursor, NN);
    count_k<<<(NE + 255) / 256, 256, 0, stream>>>(edges, flag, deg, NE);
    dinv_k<<<(NN + 255) / 256, 256, 0, stream>>>(deg, dinv, NN);
    scan_k<<<1, 1024, 0, stream>>>(deg, rp, NN);
    scatter_k<<<(NE + 255) / 256, 256, 0, stream>>>(edges, flag, rp, cursor, col_s, NE);
    // degree-sorted perm
    hzero_k<<<1, 1024, 0, stream>>>(hist);
    hist_k<<<(NN + 255) / 256, 256, 0, stream>>>(deg, hist, NN);
    hscan_k<<<1, 1024, 0, stream>>>(hist, bcur);
    pscatter_k<<<(NN + 255) / 256, 256, 0, stream>>>(deg, bcur, perm, NN);

    int mblk = (NN + 127) / 128;                 // 391
    int gemmBigGrid = ((mblk + 7) / 8) * 16;     // 800 (pair-swizzled, 2 col blocks)
    int agg256Grid = ((NN + 63) / 64) * 8;       // 6256  (64 nodes/block, 4 lanes/node)
    int agg128Grid = ((NN + 127) / 128) * 8;     // 3128  (128 nodes/block, 2 lanes/node)

    // Layer 1
    wconv3_k<<<256, 256, 0, stream>>>(W1, B3, 256);
    gemm_f16_k<2, 32><<<gemmBigGrid, 256, 0, stream>>>(Xh, Xl, B3, dinv, H, NN, 256);
    aggregate_slice_k<256, 0><<<agg256Grid, 256, 0, stream>>>(H, b1, dinv, rp, col_s, perm,
                                                              Xh, Xl, nullptr, NN);
    // Layer 2
    wconv3_k<<<256, 256, 0, stream>>>(W2, B3, 256);
    gemm_f16_k<2, 32><<<gemmBigGrid, 256, 0, stream>>>(Xh, Xl, B3, dinv, H, NN, 256);
    aggregate_slice_k<256, 0><<<agg256Grid, 256, 0, stream>>>(H, b2, dinv, rp, col_s, perm,
                                                              Xh, Xl, nullptr, NN);
    // Layer 3
    wconv3_k<<<128, 256, 0, stream>>>(W3, B3, 128);
    gemm_f16_k<1, 16><<<mblk, 256, 0, stream>>>(Xh, Xl, B3, dinv, H, NN, 128);
    aggregate_slice_k<128, 1><<<agg128Grid, 256, 0, stream>>>(H, b3, dinv, rp, col_s, perm,
                                                              nullptr, nullptr, out, NN);
}

// Round 9
// 512.122 us; speedup vs baseline: 1.5449x; 1.5449x over previous
//
#include <hip/hip_runtime.h>
#include <cstdint>
#include <cstddef>

#define NN 50000
#define NE 800000
#define NBLK ((NN + 255) / 256)   // 196 node-chunks for the sort passes

typedef _Float16 f16x8 __attribute__((ext_vector_type(8)));
typedef _Float16 f16x4 __attribute__((ext_vector_type(4)));
typedef float f32x4 __attribute__((ext_vector_type(4)));

// ---------------------------------------------------------------------------
// Edge-index dtype robustness (int64 vs int32 canonicalization)
// ---------------------------------------------------------------------------
__device__ __forceinline__ int edge_at(const void* e, int is32, long long i) {
    return is32 ? ((const int*)e)[i] : (int)((const long long*)e)[i];
}

__global__ __launch_bounds__(64) void zero_flag_k(int* flag) {
    if (threadIdx.x == 0) *flag = 0;
}

__global__ __launch_bounds__(256) void detect_k(const int* __restrict__ w, int* __restrict__ flag) {
    int i = blockIdx.x * 256 + threadIdx.x;   // 0..1023
    if (i < 1024 && w[2 * i + 1] != 0) atomicOr(flag, 1);
}

// ---------------------------------------------------------------------------
// Hadamard: X0 = qe*obj, fp16 hi/lo split, written SLICE-MAJOR:
// X[panel][node][32], panel = col>>5.
// ---------------------------------------------------------------------------
__global__ __launch_bounds__(256) void hadamard_k(const float4* __restrict__ a,
                                                  const float4* __restrict__ b,
                                                  _Float16* __restrict__ Xh,
                                                  _Float16* __restrict__ Xl, int n4) {
    int i = blockIdx.x * 256 + threadIdx.x;
    if (i >= n4) return;
    float4 x = a[i], y = b[i];
    float v[4] = { x.x * y.x, x.y * y.y, x.z * y.z, x.w * y.w };
    f16x4 hh, ll;
    #pragma unroll
    for (int j = 0; j < 4; ++j) {
        _Float16 h = (_Float16)v[j];
        hh[j] = h;
        ll[j] = (_Float16)(v[j] - (float)h);
    }
    int row = i >> 6;              // 64 float4 per 256-col row
    int cq  = (i & 63) * 4;        // col base
    size_t off = ((size_t)(cq >> 5) * NN + row) * 32 + (cq & 31);
    *(f16x4*)&Xh[off] = hh;
    *(f16x4*)&Xl[off] = ll;
}

// ---------------------------------------------------------------------------
// Degree / CSR build
// ---------------------------------------------------------------------------
__global__ __launch_bounds__(256) void init_k(int* __restrict__ deg, int* __restrict__ cursor, int n) {
    int i = blockIdx.x * 256 + threadIdx.x;
    if (i < n) { deg[i] = 1; cursor[i] = 0; }   // self-loop
}

__global__ __launch_bounds__(256) void count_k(const void* __restrict__ edges,
                                               const int* __restrict__ flag,
                                               int* __restrict__ deg, int e) {
    int i = blockIdx.x * 256 + threadIdx.x;
    if (i < e) {
        int is32 = *flag;
        atomicAdd(&deg[edge_at(edges, is32, i)], 1);
    }
}

__global__ __launch_bounds__(256) void dinv_k(const int* __restrict__ deg, float* __restrict__ dinv, int n) {
    int i = blockIdx.x * 256 + threadIdx.x;
    if (i < n) dinv[i] = rsqrtf((float)deg[i]);
}

__global__ __launch_bounds__(1024) void scan_k(const int* __restrict__ deg, int* __restrict__ rp, int n) {
    __shared__ int s[1024];
    int t = threadIdx.x;
    int chunk = (n + 1023) / 1024;
    int lo = t * chunk;
    int hi = lo + chunk; if (hi > n) hi = n;
    int sum = 0;
    for (int i = lo; i < hi; ++i) sum += deg[i] - 1;
    s[t] = sum;
    __syncthreads();
    for (int off = 1; off < 1024; off <<= 1) {
        int val = (t >= off) ? s[t - off] : 0;
        __syncthreads();
        s[t] += val;
        __syncthreads();
    }
    int run = (t == 0) ? 0 : s[t - 1];
    for (int i = lo; i < hi; ++i) { rp[i] = run; run += deg[i] - 1; }
    if (t == 1023) rp[n] = s[1023];
}

__global__ __launch_bounds__(256) void scatter_k(const void* __restrict__ edges,
                                                 const int* __restrict__ flag,
                                                 const int* __restrict__ rp,
                                                 int* __restrict__ cursor,
                                                 int* __restrict__ col_s, int e) {
    int i = blockIdx.x * 256 + threadIdx.x;
    if (i < e) {
        int is32 = *flag;
        int r = edge_at(edges, is32, i);
        int c = edge_at(edges, is32, (long long)NE + i);
        int pos = rp[r] + atomicAdd(&cursor[r], 1);
        col_s[pos] = c;
    }
}

// ---------------------------------------------------------------------------
// Degree-sorted node permutation, contention-free 3-phase counting sort.
// Phase A: per-block LDS histogram -> bh[blk][1024] (no global atomics).
// Phase B: per-bucket totals (tree reduce) -> exclusive bucket starts ->
//          per-(block,bucket) bases written back into bh (parallel scans).
// Phase C: LDS-atomic local rank + direct scatter (no contended atomics).
// ---------------------------------------------------------------------------
__global__ __launch_bounds__(256) void bh_k(const int* __restrict__ deg,
                                            int* __restrict__ bh, int n) {
    __shared__ int lh[1024];
    int t = threadIdx.x;
    for (int b = t; b < 1024; b += 256) lh[b] = 0;
    __syncthreads();
    int i = blockIdx.x * 256 + t;
    if (i < n) atomicAdd(&lh[min(deg[i], 1023)], 1);
    __syncthreads();
    for (int b = t; b < 1024; b += 256) bh[(size_t)blockIdx.x * 1024 + b] = lh[b];
}

__global__ __launch_bounds__(256) void btot_k(const int* __restrict__ bh,
                                              int* __restrict__ tot, int nb) {
    __shared__ int red[256];
    int b = blockIdx.x, t = threadIdx.x;
    int s = 0;
    for (int blk = t; blk < nb; blk += 256) s += bh[(size_t)blk * 1024 + b];
    red[t] = s;
    __syncthreads();
    for (int off = 128; off; off >>= 1) {
        if (t < off) red[t] += red[t + off];
        __syncthreads();
    }
    if (t == 0) tot[b] = red[0];
}

__global__ __launch_bounds__(1024) void hscan_k(const int* __restrict__ hist,
                                                int* __restrict__ bcur) {
    __shared__ int s[1024];
    int t = threadIdx.x;
    s[t] = hist[t];
    __syncthreads();
    for (int off = 1; off < 1024; off <<= 1) {
        int val = (t >= off) ? s[t - off] : 0;
        __syncthreads();
        s[t] += val;
        __syncthreads();
    }
    bcur[t] = (t == 0) ? 0 : s[t - 1];
}

__global__ __launch_bounds__(256) void bbase_k(int* __restrict__ bh,
                                               const int* __restrict__ bstart, int nb) {
    __shared__ int s[256];
    int b = blockIdx.x, t = threadIdx.x;
    int v = (t < nb) ? bh[(size_t)t * 1024 + b] : 0;
    s[t] = v;
    __syncthreads();
    for (int off = 1; off < 256; off <<= 1) {
        int x = (t >= off) ? s[t - off] : 0;
        __syncthreads();
        s[t] += x;
        __syncthreads();
    }
    int excl = (t == 0) ? 0 : s[t - 1];
    if (t < nb) bh[(size_t)t * 1024 + b] = bstart[b] + excl;
}

__global__ __launch_bounds__(256) void pscatter_k(const int* __restrict__ deg,
                                                  const int* __restrict__ bh,
                                                  int* __restrict__ perm, int n) {
    __shared__ int lh[1024];
    int t = threadIdx.x;
    for (int b = t; b < 1024; b += 256) lh[b] = 0;
    __syncthreads();
    int i = blockIdx.x * 256 + t;
    int b = 0, r = 0;
    if (i < n) {
        b = min(deg[i], 1023);
        r = atomicAdd(&lh[b], 1);
    }
    __syncthreads();
    if (i < n) perm[bh[(size_t)blockIdx.x * 1024 + b] + r] = i;
}

// ---------------------------------------------------------------------------
// W convert: W[K=256][Nout] fp32 -> B3 [Nout][768] fp16, layout [Wh | Wl | Wh]
// ---------------------------------------------------------------------------
__global__ __launch_bounds__(256) void wconv3_k(const float* __restrict__ W,
                                                _Float16* __restrict__ B3, int Nout) {
    int n = blockIdx.x;            // 0..Nout-1
    int k = threadIdx.x;           // 0..255
    float v = W[(size_t)k * Nout + n];
    _Float16 h = (_Float16)v;
    _Float16 l = (_Float16)(v - (float)h);
    B3[(size_t)n * 768 + k]       = h;
    B3[(size_t)n * 768 + 256 + k] = l;
    B3[(size_t)n * 768 + 512 + k] = h;
}

// ---------------------------------------------------------------------------
// fp16 MFMA GEMM over virtual K=768, slice-major A & C.
// Epilogue writes G = dinv[row] * (A@W)  (pre-scaled for the gather step).
// ---------------------------------------------------------------------------
__device__ __forceinline__ void gload_lds16(const void* g, void* l) {
    __builtin_amdgcn_global_load_lds(
        (const __attribute__((address_space(1))) void*)g,
        (__attribute__((address_space(3))) void*)l, 16, 0, 0);
}

template <int NBX, int SW>
__global__ __launch_bounds__(256) void gemm_f16_k(const _Float16* __restrict__ Ah,
                                                  const _Float16* __restrict__ Al,
                                                  const _Float16* __restrict__ B3,
                                                  const float* __restrict__ dinv,
                                                  _Float16* __restrict__ C,
                                                  int M, int Nout) {
    __shared__ alignas(16) _Float16 sA[128 * 32];   // linear: row r at r*32, 64B rows
    __shared__ alignas(16) _Float16 sB[128 * 32];
    constexpr int LG = (SW == 32) ? 5 : 4;
    int mblk = (M + 127) >> 7;

    int pair, xb;
    if (NBX == 2) {
        int b = blockIdx.x;
        pair = (b >> 4) * 8 + (b & 7);     // row-panel id; pinned to XCD (b&7)
        xb   = (b >> 3) & 1;
        if (pair >= mblk) return;
    } else {
        pair = blockIdx.x;
        xb = 0;
    }

    int tid = threadIdx.x;
    int row0 = pair * 128, col0 = xb * 128;
    int wid = tid >> 6, lane = tid & 63;
    int wm = wid >> 1, wn = wid & 1;
    int fr = lane & 15;
    int kb = (lane >> 4) * 8;       // k element base within 32

    int sr = lane >> 2;
    int ke = (lane & 3) * 8;

    f32x4 acc[4][4] = {};

    for (int s = 0; s < 24; ++s) {
        int seg = s >> 3;                 // 0: Ah, 1: Ah (L2-hot), 2: Al
        int p = s & 7;                    // A k-panel index
        const _Float16* Asrc = (seg == 2) ? Al : Ah;

        __syncthreads();                  // LDS reuse: prior reads done
        #pragma unroll
        for (int c = 0; c < 2; ++c) {
            int ch = wid * 2 + c;         // 0..7
            int r = ch * 16 + sr;
            int arow = row0 + r;
            if (arow < M)
                gload_lds16(&Asrc[((size_t)p * M + arow) * 32 + ke], &sA[ch * 512]);
            gload_lds16(&B3[(size_t)(col0 + r) * 768 + s * 32 + ke], &sB[ch * 512]);
        }
        __syncthreads();                  // drains vmcnt (global_load_lds) too

        f16x8 af[4];
        #pragma unroll
        for (int f = 0; f < 4; ++f)
            af[f] = *(const f16x8*)&sA[(wm * 64 + f * 16 + fr) * 32 + kb];
        #pragma unroll
        for (int g = 0; g < 4; ++g) {
            f16x8 bf_ = *(const f16x8*)&sB[(wn * 64 + g * 16 + fr) * 32 + kb];
            #pragma unroll
            for (int f = 0; f < 4; ++f)
                acc[f][g] = __builtin_amdgcn_mfma_f32_16x16x32_f16(af[f], bf_, acc[f][g], 0, 0, 0);
        }
    }

    int rsub = (lane >> 4) * 4;
    float dsc[4][4];
    #pragma unroll
    for (int f = 0; f < 4; ++f)
        #pragma unroll
        for (int r = 0; r < 4; ++r) {
            int row = row0 + wm * 64 + f * 16 + rsub + r;
            dsc[f][r] = (row < M) ? dinv[row] : 0.0f;
        }
    #pragma unroll
    for (int f = 0; f < 4; ++f) {
        #pragma unroll
        for (int g = 0; g < 4; ++g) {
            int col = col0 + wn * 64 + g * 16 + fr;
            #pragma unroll
            for (int r = 0; r < 4; ++r) {
                int row = row0 + wm * 64 + f * 16 + rsub + r;
                if (row < M)
                    C[((size_t)(col >> LG) * M + row) * SW + (col & (SW - 1))] =
                        (_Float16)(acc[f][g][r] * dsc[f][r]);
            }
        }
    }
}

// ---------------------------------------------------------------------------
// XCD-sliced aggregation v6: gathers pre-scaled G = diag(dinv)*H (slice-major
// fp16). out[v] = dinv[v]*(G[v] + sum_edges G[c]) + b -- per edge: ONE gather,
// one add chain. Nodes processed in degree-sorted order via perm -> wave
// max-degree ~= mean. MODE 0: relu, slice-major fp16 hi/lo out. MODE 1: fp32.
// ---------------------------------------------------------------------------
template <int D, int MODE>
__global__ __launch_bounds__(256) void aggregate_slice_k(const _Float16* __restrict__ G,
                                                         const float* __restrict__ bias,
                                                         const float* __restrict__ dinv,
                                                         const int* __restrict__ rp,
                                                         const int* __restrict__ cs,
                                                         const int* __restrict__ perm,
                                                         _Float16* __restrict__ Yh,
                                                         _Float16* __restrict__ Yl,
                                                         float* __restrict__ Yf, int n) {
    constexpr int SLICE = (D == 256) ? 32 : 16;   // panel width
    constexpr int LPN = SLICE / 8;                // lanes per node (f16x8 each)
    constexpr int NPB = 256 / LPN;                // nodes per block

    int bid = blockIdx.x;
    int s = bid & 7;
    int slot = (bid >> 3) * NPB + threadIdx.x / LPN;
    if (slot >= n) return;
    int v = perm[slot];
    int sub = threadIdx.x % LPN;
    int co = sub * 8;                             // within-panel col offset
    int col = s * SLICE + co;                     // global col (bias / out)

    const _Float16* Gs = G + (size_t)s * n * SLICE;   // this slice's panel

    float acc[8];
    {
        f16x8 t0 = *(const f16x8*)&Gs[(size_t)v * SLICE + co];
        #pragma unroll
        for (int i = 0; i < 8; ++i) acc[i] = (float)t0[i];
    }

    int beg = rp[v], end = rp[v + 1];
    int j = beg;
    for (; j + 8 <= end; j += 8) {
        int cc[8];
        #pragma unroll
        for (int u = 0; u < 8; ++u) cc[u] = cs[j + u];
        f16x8 hv[8];
        #pragma unroll
        for (int u = 0; u < 8; ++u)
            hv[u] = *(const f16x8*)&Gs[(size_t)cc[u] * SLICE + co];
        #pragma unroll
        for (int u = 0; u < 8; ++u)
            #pragma unroll
            for (int i = 0; i < 8; ++i)
                acc[i] += (float)hv[u][i];
    }
    for (; j < end; ++j) {
        int c = cs[j];
        f16x8 a = *(const f16x8*)&Gs[(size_t)c * SLICE + co];
        #pragma unroll
        for (int i = 0; i < 8; ++i) acc[i] += (float)a[i];
    }

    float dv = dinv[v];
    float4 b0 = *(const float4*)&bias[col];
    float4 b1 = *(const float4*)&bias[col + 4];
    float bb[8] = { b0.x, b0.y, b0.z, b0.w, b1.x, b1.y, b1.z, b1.w };

    if constexpr (MODE == 0) {
        f16x8 hh, ll;
        #pragma unroll
        for (int i = 0; i < 8; ++i) {
            float o = fmaxf(dv * acc[i] + bb[i], 0.0f);
            _Float16 h = (_Float16)o;
            hh[i] = h;
            ll[i] = (_Float16)(o - (float)h);
        }
        size_t off = ((size_t)s * n + v) * SLICE + co;   // slice-major out
        *(f16x8*)&Yh[off] = hh;
        *(f16x8*)&Yl[off] = ll;
    } else {
        float o[8];
        #pragma unroll
        for (int i = 0; i < 8; ++i) o[i] = dv * acc[i] + bb[i];
        *(float4*)&Yf[(size_t)v * D + col]     = make_float4(o[0], o[1], o[2], o[3]);
        *(float4*)&Yf[(size_t)v * D + col + 4] = make_float4(o[4], o[5], o[6], o[7]);
    }
}

// ---------------------------------------------------------------------------
extern "C" void kernel_launch(void* const* d_in, const int* in_sizes, int n_in,
                              void* d_out, int out_size, void* d_ws, size_t ws_size,
                              hipStream_t stream) {
    const float* qe  = (const float*)d_in[0];
    const float* obj = (const float*)d_in[1];
    const void*  edges = d_in[2];
    const float* W1 = (const float*)d_in[3];
    const float* b1 = (const float*)d_in[4];
    const float* W2 = (const float*)d_in[5];
    const float* b2 = (const float*)d_in[6];
    const float* W3 = (const float*)d_in[7];
    const float* b3 = (const float*)d_in[8];
    float* out = (float*)d_out;

    char* p = (char*)d_ws;
    _Float16* Xh   = (_Float16*)p; p += (size_t)NN * 256 * 2;   // 25.6 MB (slice-major)
    _Float16* Xl   = (_Float16*)p; p += (size_t)NN * 256 * 2;   // 25.6 MB (slice-major)
    _Float16* H    = (_Float16*)p; p += (size_t)NN * 256 * 2;   // 25.6 MB (slice-major G)
    _Float16* B3   = (_Float16*)p; p += (size_t)256 * 768 * 2;  // 0.4 MB
    int*   deg     = (int*)p;   p += (size_t)NN * 4;
    float* dinv    = (float*)p; p += (size_t)NN * 4;
    int*   rp      = (int*)p;   p += (size_t)(NN + 1) * 4;
    int*   cursor  = (int*)p;   p += (size_t)NN * 4;
    int*   col_s   = (int*)p;   p += (size_t)NE * 4;
    int*   bh      = (int*)p;   p += (size_t)NBLK * 1024 * 4;   // 0.8 MB
    int*   tot     = (int*)p;   p += 1024 * 4;
    int*   bstart  = (int*)p;   p += 1024 * 4;
    int*   perm    = (int*)p;   p += (size_t)NN * 4;
    int*   flag    = (int*)p;   p += 4;

    zero_flag_k<<<1, 64, 0, stream>>>(flag);
    detect_k<<<4, 256, 0, stream>>>((const int*)edges, flag);
    hadamard_k<<<(NN * 64 + 255) / 256, 256, 0, stream>>>(
        (const float4*)qe, (const float4*)obj, Xh, Xl, NN * 64);
    init_k<<<(NN + 255) / 256, 256, 0, stream>>>(deg, cursor, NN);
    count_k<<<(NE + 255) / 256, 256, 0, stream>>>(edges, flag, deg, NE);
    dinv_k<<<(NN + 255) / 256, 256, 0, stream>>>(deg, dinv, NN);
    scan_k<<<1, 1024, 0, stream>>>(deg, rp, NN);
    scatter_k<<<(NE + 255) / 256, 256, 0, stream>>>(edges, flag, rp, cursor, col_s, NE);
    // degree-sorted perm (contention-free counting sort)
    bh_k<<<NBLK, 256, 0, stream>>>(deg, bh, NN);
    btot_k<<<1024, 256, 0, stream>>>(bh, tot, NBLK);
    hscan_k<<<1, 1024, 0, stream>>>(tot, bstart);
    bbase_k<<<1024, 256, 0, stream>>>(bh, bstart, NBLK);
    pscatter_k<<<NBLK, 256, 0, stream>>>(deg, bh, perm, NN);

    int mblk = (NN + 127) / 128;                 // 391
    int gemmBigGrid = ((mblk + 7) / 8) * 16;     // 800 (pair-swizzled, 2 col blocks)
    int agg256Grid = ((NN + 63) / 64) * 8;       // 6256  (64 nodes/block, 4 lanes/node)
    int agg128Grid = ((NN + 127) / 128) * 8;     // 3128  (128 nodes/block, 2 lanes/node)

    // Layer 1
    wconv3_k<<<256, 256, 0, stream>>>(W1, B3, 256);
    gemm_f16_k<2, 32><<<gemmBigGrid, 256, 0, stream>>>(Xh, Xl, B3, dinv, H, NN, 256);
    aggregate_slice_k<256, 0><<<agg256Grid, 256, 0, stream>>>(H, b1, dinv, rp, col_s, perm,
                                                              Xh, Xl, nullptr, NN);
    // Layer 2
    wconv3_k<<<256, 256, 0, stream>>>(W2, B3, 256);
    gemm_f16_k<2, 32><<<gemmBigGrid, 256, 0, stream>>>(Xh, Xl, B3, dinv, H, NN, 256);
    aggregate_slice_k<256, 0><<<agg256Grid, 256, 0, stream>>>(H, b2, dinv, rp, col_s, perm,
                                                              Xh, Xl, nullptr, NN);
    // Layer 3
    wconv3_k<<<128, 256, 0, stream>>>(W3, B3, 128);
    gemm_f16_k<1, 16><<<mblk, 256, 0, stream>>>(Xh, Xl, B3, dinv, H, NN, 128);
    aggregate_slice_k<128, 1><<<agg128Grid, 256, 0, stream>>>(H, b3, dinv, rp, col_s, perm,
                                                              nullptr, nullptr, out, NN);
}

// Round 10
// 446.480 us; speedup vs baseline: 1.7721x; 1.1470x over previous
//
#include <hip/hip_runtime.h>
#include <cstdint>
#include <cstddef>

#define NN 50000
#define NE 800000
#define NBLK ((NN + 255) / 256)   // 196 node-chunks

typedef _Float16 f16x8 __attribute__((ext_vector_type(8)));
typedef _Float16 f16x4 __attribute__((ext_vector_type(4)));
typedef float f32x4 __attribute__((ext_vector_type(4)));

// ---------------------------------------------------------------------------
// Edge-index dtype robustness (int64 vs int32 canonicalization)
// ---------------------------------------------------------------------------
__device__ __forceinline__ int edge_at(const void* e, int is32, long long i) {
    return is32 ? ((const int*)e)[i] : (int)((const long long*)e)[i];
}

__global__ __launch_bounds__(64) void zero_flag_k(int* flag) {
    if (threadIdx.x == 0) *flag = 0;
}

__global__ __launch_bounds__(256) void detect_k(const int* __restrict__ w, int* __restrict__ flag) {
    int i = blockIdx.x * 256 + threadIdx.x;   // 0..1023
    if (i < 1024 && w[2 * i + 1] != 0) atomicOr(flag, 1);
}

// ---------------------------------------------------------------------------
// Hadamard: X0 = qe*obj, fp16 hi/lo split, written SLICE-MAJOR:
// X[panel][node][32], panel = col>>5.
// ---------------------------------------------------------------------------
__global__ __launch_bounds__(256) void hadamard_k(const float4* __restrict__ a,
                                                  const float4* __restrict__ b,
                                                  _Float16* __restrict__ Xh,
                                                  _Float16* __restrict__ Xl, int n4) {
    int i = blockIdx.x * 256 + threadIdx.x;
    if (i >= n4) return;
    float4 x = a[i], y = b[i];
    float v[4] = { x.x * y.x, x.y * y.y, x.z * y.z, x.w * y.w };
    f16x4 hh, ll;
    #pragma unroll
    for (int j = 0; j < 4; ++j) {
        _Float16 h = (_Float16)v[j];
        hh[j] = h;
        ll[j] = (_Float16)(v[j] - (float)h);
    }
    int row = i >> 6;              // 64 float4 per 256-col row
    int cq  = (i & 63) * 4;        // col base
    size_t off = ((size_t)(cq >> 5) * NN + row) * 32 + (cq & 31);
    *(f16x4*)&Xh[off] = hh;
    *(f16x4*)&Xl[off] = ll;
}

// ---------------------------------------------------------------------------
// Degree / CSR build
// ---------------------------------------------------------------------------
__global__ __launch_bounds__(256) void init_k(int* __restrict__ deg, int* __restrict__ cursor, int n) {
    int i = blockIdx.x * 256 + threadIdx.x;
    if (i < n) { deg[i] = 1; cursor[i] = 0; }   // self-loop
}

__global__ __launch_bounds__(256) void count_k(const void* __restrict__ edges,
                                               const int* __restrict__ flag,
                                               int* __restrict__ deg, int e) {
    int i = blockIdx.x * 256 + threadIdx.x;
    if (i < e) {
        int is32 = *flag;
        atomicAdd(&deg[edge_at(edges, is32, i)], 1);
    }
}

__global__ __launch_bounds__(256) void dinv_k(const int* __restrict__ deg, float* __restrict__ dinv, int n) {
    int i = blockIdx.x * 256 + threadIdx.x;
    if (i < n) dinv[i] = rsqrtf((float)deg[i]);
}

// ---------------------------------------------------------------------------
// Device-wide exclusive scan of (deg[i]-1) -> rp[0..n], 3-phase parallel.
// Replaces the single-block scan_k (was 77 us on the serial chain).
// ---------------------------------------------------------------------------
__global__ __launch_bounds__(256) void ppart_k(const int* __restrict__ deg,
                                               int* __restrict__ part, int n) {
    __shared__ int red[256];
    int t = threadIdx.x;
    int i = blockIdx.x * 256 + t;
    red[t] = (i < n) ? deg[i] - 1 : 0;
    __syncthreads();
    for (int off = 128; off; off >>= 1) {
        if (t < off) red[t] += red[t + off];
        __syncthreads();
    }
    if (t == 0) part[blockIdx.x] = red[0];
}

__global__ __launch_bounds__(256) void pscan1_k(int* __restrict__ part, int nb) {
    __shared__ int s[256];
    int t = threadIdx.x;
    s[t] = (t < nb) ? part[t] : 0;
    __syncthreads();
    for (int off = 1; off < 256; off <<= 1) {
        int v = (t >= off) ? s[t - off] : 0;
        __syncthreads();
        s[t] += v;
        __syncthreads();
    }
    if (t < nb) part[t] = (t == 0) ? 0 : s[t - 1];
}

__global__ __launch_bounds__(256) void pwrite_k(const int* __restrict__ deg,
                                                const int* __restrict__ part,
                                                int* __restrict__ rp, int n) {
    __shared__ int s[256];
    int t = threadIdx.x;
    int i = blockIdx.x * 256 + t;
    int val = (i < n) ? deg[i] - 1 : 0;
    s[t] = val;
    __syncthreads();
    for (int off = 1; off < 256; off <<= 1) {
        int v = (t >= off) ? s[t - off] : 0;
        __syncthreads();
        s[t] += v;
        __syncthreads();
    }
    int incl = s[t];
    if (i < n) rp[i] = part[blockIdx.x] + incl - val;
    if (i == n - 1) rp[n] = part[blockIdx.x] + incl;
}

__global__ __launch_bounds__(256) void scatter_k(const void* __restrict__ edges,
                                                 const int* __restrict__ flag,
                                                 const int* __restrict__ rp,
                                                 int* __restrict__ cursor,
                                                 int* __restrict__ col_s, int e) {
    int i = blockIdx.x * 256 + threadIdx.x;
    if (i < e) {
        int is32 = *flag;
        int r = edge_at(edges, is32, i);
        int c = edge_at(edges, is32, (long long)NE + i);
        int pos = rp[r] + atomicAdd(&cursor[r], 1);
        col_s[pos] = c;
    }
}

// ---------------------------------------------------------------------------
// Degree-sorted node permutation, contention-free 3-phase counting sort.
// ---------------------------------------------------------------------------
__global__ __launch_bounds__(256) void bh_k(const int* __restrict__ deg,
                                            int* __restrict__ bh, int n) {
    __shared__ int lh[1024];
    int t = threadIdx.x;
    for (int b = t; b < 1024; b += 256) lh[b] = 0;
    __syncthreads();
    int i = blockIdx.x * 256 + t;
    if (i < n) atomicAdd(&lh[min(deg[i], 1023)], 1);
    __syncthreads();
    for (int b = t; b < 1024; b += 256) bh[(size_t)blockIdx.x * 1024 + b] = lh[b];
}

__global__ __launch_bounds__(256) void btot_k(const int* __restrict__ bh,
                                              int* __restrict__ tot, int nb) {
    __shared__ int red[256];
    int b = blockIdx.x, t = threadIdx.x;
    int s = 0;
    for (int blk = t; blk < nb; blk += 256) s += bh[(size_t)blk * 1024 + b];
    red[t] = s;
    __syncthreads();
    for (int off = 128; off; off >>= 1) {
        if (t < off) red[t] += red[t + off];
        __syncthreads();
    }
    if (t == 0) tot[b] = red[0];
}

__global__ __launch_bounds__(1024) void hscan_k(const int* __restrict__ hist,
                                                int* __restrict__ bcur) {
    __shared__ int s[1024];
    int t = threadIdx.x;
    s[t] = hist[t];
    __syncthreads();
    for (int off = 1; off < 1024; off <<= 1) {
        int val = (t >= off) ? s[t - off] : 0;
        __syncthreads();
        s[t] += val;
        __syncthreads();
    }
    bcur[t] = (t == 0) ? 0 : s[t - 1];
}

__global__ __launch_bounds__(256) void bbase_k(int* __restrict__ bh,
                                               const int* __restrict__ bstart, int nb) {
    __shared__ int s[256];
    int b = blockIdx.x, t = threadIdx.x;
    int v = (t < nb) ? bh[(size_t)t * 1024 + b] : 0;
    s[t] = v;
    __syncthreads();
    for (int off = 1; off < 256; off <<= 1) {
        int x = (t >= off) ? s[t - off] : 0;
        __syncthreads();
        s[t] += x;
        __syncthreads();
    }
    int excl = (t == 0) ? 0 : s[t - 1];
    if (t < nb) bh[(size_t)t * 1024 + b] = bstart[b] + excl;
}

__global__ __launch_bounds__(256) void pscatter_k(const int* __restrict__ deg,
                                                  const int* __restrict__ bh,
                                                  int* __restrict__ perm, int n) {
    __shared__ int lh[1024];
    int t = threadIdx.x;
    for (int b = t; b < 1024; b += 256) lh[b] = 0;
    __syncthreads();
    int i = blockIdx.x * 256 + t;
    int b = 0, r = 0;
    if (i < n) {
        b = min(deg[i], 1023);
        r = atomicAdd(&lh[b], 1);
    }
    __syncthreads();
    if (i < n) perm[bh[(size_t)blockIdx.x * 1024 + b] + r] = i;
}

// ---------------------------------------------------------------------------
// W convert: W[K=256][Nout] fp32 -> B3 [Nout][768] fp16, layout [Wh | Wl | Wh]
// ---------------------------------------------------------------------------
__global__ __launch_bounds__(256) void wconv3_k(const float* __restrict__ W,
                                                _Float16* __restrict__ B3, int Nout) {
    int n = blockIdx.x;            // 0..Nout-1
    int k = threadIdx.x;           // 0..255
    float v = W[(size_t)k * Nout + n];
    _Float16 h = (_Float16)v;
    _Float16 l = (_Float16)(v - (float)h);
    B3[(size_t)n * 768 + k]       = h;
    B3[(size_t)n * 768 + 256 + k] = l;
    B3[(size_t)n * 768 + 512 + k] = h;
}

// ---------------------------------------------------------------------------
// fp16 MFMA GEMM over virtual K=768, slice-major A & C.
// Epilogue writes G = dinv[row] * (A@W)  (pre-scaled for the gather step).
// ---------------------------------------------------------------------------
__device__ __forceinline__ void gload_lds16(const void* g, void* l) {
    __builtin_amdgcn_global_load_lds(
        (const __attribute__((address_space(1))) void*)g,
        (__attribute__((address_space(3))) void*)l, 16, 0, 0);
}

template <int NBX, int SW>
__global__ __launch_bounds__(256) void gemm_f16_k(const _Float16* __restrict__ Ah,
                                                  const _Float16* __restrict__ Al,
                                                  const _Float16* __restrict__ B3,
                                                  const float* __restrict__ dinv,
                                                  _Float16* __restrict__ C,
                                                  int M, int Nout) {
    __shared__ alignas(16) _Float16 sA[128 * 32];   // linear: row r at r*32, 64B rows
    __shared__ alignas(16) _Float16 sB[128 * 32];
    constexpr int LG = (SW == 32) ? 5 : 4;
    int mblk = (M + 127) >> 7;

    int pair, xb;
    if (NBX == 2) {
        int b = blockIdx.x;
        pair = (b >> 4) * 8 + (b & 7);     // row-panel id; pinned to XCD (b&7)
        xb   = (b >> 3) & 1;
        if (pair >= mblk) return;
    } else {
        pair = blockIdx.x;
        xb = 0;
    }

    int tid = threadIdx.x;
    int row0 = pair * 128, col0 = xb * 128;
    int wid = tid >> 6, lane = tid & 63;
    int wm = wid >> 1, wn = wid & 1;
    int fr = lane & 15;
    int kb = (lane >> 4) * 8;       // k element base within 32

    int sr = lane >> 2;
    int ke = (lane & 3) * 8;

    f32x4 acc[4][4] = {};

    for (int s = 0; s < 24; ++s) {
        int seg = s >> 3;                 // 0: Ah, 1: Ah (L2-hot), 2: Al
        int p = s & 7;                    // A k-panel index
        const _Float16* Asrc = (seg == 2) ? Al : Ah;

        __syncthreads();                  // LDS reuse: prior reads done
        #pragma unroll
        for (int c = 0; c < 2; ++c) {
            int ch = wid * 2 + c;         // 0..7
            int r = ch * 16 + sr;
            int arow = row0 + r;
            if (arow < M)
                gload_lds16(&Asrc[((size_t)p * M + arow) * 32 + ke], &sA[ch * 512]);
            gload_lds16(&B3[(size_t)(col0 + r) * 768 + s * 32 + ke], &sB[ch * 512]);
        }
        __syncthreads();                  // drains vmcnt (global_load_lds) too

        f16x8 af[4];
        #pragma unroll
        for (int f = 0; f < 4; ++f)
            af[f] = *(const f16x8*)&sA[(wm * 64 + f * 16 + fr) * 32 + kb];
        #pragma unroll
        for (int g = 0; g < 4; ++g) {
            f16x8 bf_ = *(const f16x8*)&sB[(wn * 64 + g * 16 + fr) * 32 + kb];
            #pragma unroll
            for (int f = 0; f < 4; ++f)
                acc[f][g] = __builtin_amdgcn_mfma_f32_16x16x32_f16(af[f], bf_, acc[f][g], 0, 0, 0);
        }
    }

    int rsub = (lane >> 4) * 4;
    float dsc[4][4];
    #pragma unroll
    for (int f = 0; f < 4; ++f)
        #pragma unroll
        for (int r = 0; r < 4; ++r) {
            int row = row0 + wm * 64 + f * 16 + rsub + r;
            dsc[f][r] = (row < M) ? dinv[row] : 0.0f;
        }
    #pragma unroll
    for (int f = 0; f < 4; ++f) {
        #pragma unroll
        for (int g = 0; g < 4; ++g) {
            int col = col0 + wn * 64 + g * 16 + fr;
            #pragma unroll
            for (int r = 0; r < 4; ++r) {
                int row = row0 + wm * 64 + f * 16 + rsub + r;
                if (row < M)
                    C[((size_t)(col >> LG) * M + row) * SW + (col & (SW - 1))] =
                        (_Float16)(acc[f][g][r] * dsc[f][r]);
            }
        }
    }
}

// ---------------------------------------------------------------------------
// XCD-sliced aggregation v6: gathers pre-scaled G = diag(dinv)*H (slice-major
// fp16). out[v] = dinv[v]*(G[v] + sum_edges G[c]) + b -- per edge: ONE gather,
// one add chain. Nodes processed in degree-sorted order via perm -> wave
// max-degree ~= mean. MODE 0: relu, slice-major fp16 hi/lo out. MODE 1: fp32.
// ---------------------------------------------------------------------------
template <int D, int MODE>
__global__ __launch_bounds__(256) void aggregate_slice_k(const _Float16* __restrict__ G,
                                                         const float* __restrict__ bias,
                                                         const float* __restrict__ dinv,
                                                         const int* __restrict__ rp,
                                                         const int* __restrict__ cs,
                                                         const int* __restrict__ perm,
                                                         _Float16* __restrict__ Yh,
                                                         _Float16* __restrict__ Yl,
                                                         float* __restrict__ Yf, int n) {
    constexpr int SLICE = (D == 256) ? 32 : 16;   // panel width
    constexpr int LPN = SLICE / 8;                // lanes per node (f16x8 each)
    constexpr int NPB = 256 / LPN;                // nodes per block

    int bid = blockIdx.x;
    int s = bid & 7;
    int slot = (bid >> 3) * NPB + threadIdx.x / LPN;
    if (slot >= n) return;
    int v = perm[slot];
    int sub = threadIdx.x % LPN;
    int co = sub * 8;                             // within-panel col offset
    int col = s * SLICE + co;                     // global col (bias / out)

    const _Float16* Gs = G + (size_t)s * n * SLICE;   // this slice's panel

    float acc[8];
    {
        f16x8 t0 = *(const f16x8*)&Gs[(size_t)v * SLICE + co];
        #pragma unroll
        for (int i = 0; i < 8; ++i) acc[i] = (float)t0[i];
    }

    int beg = rp[v], end = rp[v + 1];
    int j = beg;
    for (; j + 8 <= end; j += 8) {
        int cc[8];
        #pragma unroll
        for (int u = 0; u < 8; ++u) cc[u] = cs[j + u];
        f16x8 hv[8];
        #pragma unroll
        for (int u = 0; u < 8; ++u)
            hv[u] = *(const f16x8*)&Gs[(size_t)cc[u] * SLICE + co];
        #pragma unroll
        for (int u = 0; u < 8; ++u)
            #pragma unroll
            for (int i = 0; i < 8; ++i)
                acc[i] += (float)hv[u][i];
    }
    for (; j < end; ++j) {
        int c = cs[j];
        f16x8 a = *(const f16x8*)&Gs[(size_t)c * SLICE + co];
        #pragma unroll
        for (int i = 0; i < 8; ++i) acc[i] += (float)a[i];
    }

    float dv = dinv[v];
    float4 b0 = *(const float4*)&bias[col];
    float4 b1 = *(const float4*)&bias[col + 4];
    float bb[8] = { b0.x, b0.y, b0.z, b0.w, b1.x, b1.y, b1.z, b1.w };

    if constexpr (MODE == 0) {
        f16x8 hh, ll;
        #pragma unroll
        for (int i = 0; i < 8; ++i) {
            float o = fmaxf(dv * acc[i] + bb[i], 0.0f);
            _Float16 h = (_Float16)o;
            hh[i] = h;
            ll[i] = (_Float16)(o - (float)h);
        }
        size_t off = ((size_t)s * n + v) * SLICE + co;   // slice-major out
        *(f16x8*)&Yh[off] = hh;
        *(f16x8*)&Yl[off] = ll;
    } else {
        float o[8];
        #pragma unroll
        for (int i = 0; i < 8; ++i) o[i] = dv * acc[i] + bb[i];
        *(float4*)&Yf[(size_t)v * D + col]     = make_float4(o[0], o[1], o[2], o[3]);
        *(float4*)&Yf[(size_t)v * D + col + 4] = make_float4(o[4], o[5], o[6], o[7]);
    }
}

// ---------------------------------------------------------------------------
extern "C" void kernel_launch(void* const* d_in, const int* in_sizes, int n_in,
                              void* d_out, int out_size, void* d_ws, size_t ws_size,
                              hipStream_t stream) {
    const float* qe  = (const float*)d_in[0];
    const float* obj = (const float*)d_in[1];
    const void*  edges = d_in[2];
    const float* W1 = (const float*)d_in[3];
    const float* b1 = (const float*)d_in[4];
    const float* W2 = (const float*)d_in[5];
    const float* b2 = (const float*)d_in[6];
    const float* W3 = (const float*)d_in[7];
    const float* b3 = (const float*)d_in[8];
    float* out = (float*)d_out;

    char* p = (char*)d_ws;
    _Float16* Xh   = (_Float16*)p; p += (size_t)NN * 256 * 2;   // 25.6 MB (slice-major)
    _Float16* Xl   = (_Float16*)p; p += (size_t)NN * 256 * 2;   // 25.6 MB (slice-major)
    _Float16* H    = (_Float16*)p; p += (size_t)NN * 256 * 2;   // 25.6 MB (slice-major G)
    _Float16* B3   = (_Float16*)p; p += (size_t)256 * 768 * 2;  // 0.4 MB
    int*   deg     = (int*)p;   p += (size_t)NN * 4;
    float* dinv    = (float*)p; p += (size_t)NN * 4;
    int*   rp      = (int*)p;   p += (size_t)(NN + 1) * 4;
    int*   cursor  = (int*)p;   p += (size_t)NN * 4;
    int*   col_s   = (int*)p;   p += (size_t)NE * 4;
    int*   bh      = (int*)p;   p += (size_t)NBLK * 1024 * 4;   // 0.8 MB
    int*   tot     = (int*)p;   p += 1024 * 4;
    int*   bstart  = (int*)p;   p += 1024 * 4;
    int*   part    = (int*)p;   p += NBLK * 4;
    int*   perm    = (int*)p;   p += (size_t)NN * 4;
    int*   flag    = (int*)p;   p += 4;

    zero_flag_k<<<1, 64, 0, stream>>>(flag);
    detect_k<<<4, 256, 0, stream>>>((const int*)edges, flag);
    hadamard_k<<<(NN * 64 + 255) / 256, 256, 0, stream>>>(
        (const float4*)qe, (const float4*)obj, Xh, Xl, NN * 64);
    init_k<<<(NN + 255) / 256, 256, 0, stream>>>(deg, cursor, NN);
    count_k<<<(NE + 255) / 256, 256, 0, stream>>>(edges, flag, deg, NE);
    dinv_k<<<(NN + 255) / 256, 256, 0, stream>>>(deg, dinv, NN);
    // device-wide parallel scan for rp
    ppart_k<<<NBLK, 256, 0, stream>>>(deg, part, NN);
    pscan1_k<<<1, 256, 0, stream>>>(part, NBLK);
    pwrite_k<<<NBLK, 256, 0, stream>>>(deg, part, rp, NN);
    scatter_k<<<(NE + 255) / 256, 256, 0, stream>>>(edges, flag, rp, cursor, col_s, NE);
    // degree-sorted perm (contention-free counting sort)
    bh_k<<<NBLK, 256, 0, stream>>>(deg, bh, NN);
    btot_k<<<1024, 256, 0, stream>>>(bh, tot, NBLK);
    hscan_k<<<1, 1024, 0, stream>>>(tot, bstart);
    bbase_k<<<1024, 256, 0, stream>>>(bh, bstart, NBLK);
    pscatter_k<<<NBLK, 256, 0, stream>>>(deg, bh, perm, NN);

    int mblk = (NN + 127) / 128;                 // 391
    int gemmBigGrid = ((mblk + 7) / 8) * 16;     // 800 (pair-swizzled, 2 col blocks)
    int agg256Grid = ((NN + 63) / 64) * 8;       // 6256  (64 nodes/block, 4 lanes/node)
    int agg128Grid = ((NN + 127) / 128) * 8;     // 3128  (128 nodes/block, 2 lanes/node)

    // Layer 1
    wconv3_k<<<256, 256, 0, stream>>>(W1, B3, 256);
    gemm_f16_k<2, 32><<<gemmBigGrid, 256, 0, stream>>>(Xh, Xl, B3, dinv, H, NN, 256);
    aggregate_slice_k<256, 0><<<agg256Grid, 256, 0, stream>>>(H, b1, dinv, rp, col_s, perm,
                                                              Xh, Xl, nullptr, NN);
    // Layer 2
    wconv3_k<<<256, 256, 0, stream>>>(W2, B3, 256);
    gemm_f16_k<2, 32><<<gemmBigGrid, 256, 0, stream>>>(Xh, Xl, B3, dinv, H, NN, 256);
    aggregate_slice_k<256, 0><<<agg256Grid, 256, 0, stream>>>(H, b2, dinv, rp, col_s, perm,
                                                              Xh, Xl, nullptr, NN);
    // Layer 3
    wconv3_k<<<128, 256, 0, stream>>>(W3, B3, 128);
    gemm_f16_k<1, 16><<<mblk, 256, 0, stream>>>(Xh, Xl, B3, dinv, H, NN, 128);
    aggregate_slice_k<128, 1><<<agg128Grid, 256, 0, stream>>>(H, b3, dinv, rp, col_s, perm,
                                                              nullptr, nullptr, out, NN);
}

// Round 11
// 403.281 us; speedup vs baseline: 1.9619x; 1.1071x over previous
//
#include <hip/hip_runtime.h>
#include <cstdint>
#include <cstddef>

#define NN 50000
#define NE 800000
#define NBLK ((NN + 255) / 256)   // 196 node-chunks

typedef _Float16 f16x8 __attribute__((ext_vector_type(8)));
typedef _Float16 f16x4 __attribute__((ext_vector_type(4)));
typedef float f32x4 __attribute__((ext_vector_type(4)));

// ---------------------------------------------------------------------------
// Edge-index dtype robustness (int64 vs int32 canonicalization)
// ---------------------------------------------------------------------------
__device__ __forceinline__ int edge_at(const void* e, int is32, long long i) {
    return is32 ? ((const int*)e)[i] : (int)((const long long*)e)[i];
}

__global__ __launch_bounds__(64) void zero_flag_k(int* flag) {
    if (threadIdx.x == 0) *flag = 0;
}

__global__ __launch_bounds__(256) void detect_k(const int* __restrict__ w, int* __restrict__ flag) {
    int i = blockIdx.x * 256 + threadIdx.x;   // 0..1023
    if (i < 1024 && w[2 * i + 1] != 0) atomicOr(flag, 1);
}

// ---------------------------------------------------------------------------
// Degree count (original node ids)
// ---------------------------------------------------------------------------
__global__ __launch_bounds__(256) void init_k(int* __restrict__ deg, int* __restrict__ cursor, int n) {
    int i = blockIdx.x * 256 + threadIdx.x;
    if (i < n) { deg[i] = 1; cursor[i] = 0; }   // self-loop
}

__global__ __launch_bounds__(256) void count_k(const void* __restrict__ edges,
                                               const int* __restrict__ flag,
                                               int* __restrict__ deg, int e) {
    int i = blockIdx.x * 256 + threadIdx.x;
    if (i < e) {
        int is32 = *flag;
        atomicAdd(&deg[edge_at(edges, is32, i)], 1);
    }
}

// ---------------------------------------------------------------------------
// Degree-sorted node permutation, contention-free 3-phase counting sort.
// Produces perm (slot->orig) AND inv_perm (orig->slot): full graph renumber.
// ---------------------------------------------------------------------------
__global__ __launch_bounds__(256) void bh_k(const int* __restrict__ deg,
                                            int* __restrict__ bh, int n) {
    __shared__ int lh[1024];
    int t = threadIdx.x;
    for (int b = t; b < 1024; b += 256) lh[b] = 0;
    __syncthreads();
    int i = blockIdx.x * 256 + t;
    if (i < n) atomicAdd(&lh[min(deg[i], 1023)], 1);
    __syncthreads();
    for (int b = t; b < 1024; b += 256) bh[(size_t)blockIdx.x * 1024 + b] = lh[b];
}

__global__ __launch_bounds__(256) void btot_k(const int* __restrict__ bh,
                                              int* __restrict__ tot, int nb) {
    __shared__ int red[256];
    int b = blockIdx.x, t = threadIdx.x;
    int s = 0;
    for (int blk = t; blk < nb; blk += 256) s += bh[(size_t)blk * 1024 + b];
    red[t] = s;
    __syncthreads();
    for (int off = 128; off; off >>= 1) {
        if (t < off) red[t] += red[t + off];
        __syncthreads();
    }
    if (t == 0) tot[b] = red[0];
}

__global__ __launch_bounds__(1024) void hscan_k(const int* __restrict__ hist,
                                                int* __restrict__ bcur) {
    __shared__ int s[1024];
    int t = threadIdx.x;
    s[t] = hist[t];
    __syncthreads();
    for (int off = 1; off < 1024; off <<= 1) {
        int val = (t >= off) ? s[t - off] : 0;
        __syncthreads();
        s[t] += val;
        __syncthreads();
    }
    bcur[t] = (t == 0) ? 0 : s[t - 1];
}

__global__ __launch_bounds__(256) void bbase_k(int* __restrict__ bh,
                                               const int* __restrict__ bstart, int nb) {
    __shared__ int s[256];
    int b = blockIdx.x, t = threadIdx.x;
    int v = (t < nb) ? bh[(size_t)t * 1024 + b] : 0;
    s[t] = v;
    __syncthreads();
    for (int off = 1; off < 256; off <<= 1) {
        int x = (t >= off) ? s[t - off] : 0;
        __syncthreads();
        s[t] += x;
        __syncthreads();
    }
    int excl = (t == 0) ? 0 : s[t - 1];
    if (t < nb) bh[(size_t)t * 1024 + b] = bstart[b] + excl;
}

__global__ __launch_bounds__(256) void pscatter_k(const int* __restrict__ deg,
                                                  const int* __restrict__ bh,
                                                  int* __restrict__ perm,
                                                  int* __restrict__ inv_perm, int n) {
    __shared__ int lh[1024];
    int t = threadIdx.x;
    for (int b = t; b < 1024; b += 256) lh[b] = 0;
    __syncthreads();
    int i = blockIdx.x * 256 + t;
    int b = 0, r = 0;
    if (i < n) {
        b = min(deg[i], 1023);
        r = atomicAdd(&lh[b], 1);
    }
    __syncthreads();
    if (i < n) {
        int pos = bh[(size_t)blockIdx.x * 1024 + b] + r;
        perm[pos] = i;
        inv_perm[i] = pos;
    }
}

// slot-space degree + dinv
__global__ __launch_bounds__(256) void degs_k(const int* __restrict__ deg,
                                              const int* __restrict__ perm,
                                              int* __restrict__ deg_s,
                                              float* __restrict__ dinv_s, int n) {
    int i = blockIdx.x * 256 + threadIdx.x;
    if (i < n) {
        int d = deg[perm[i]];
        deg_s[i] = d;
        dinv_s[i] = rsqrtf((float)d);
    }
}

// ---------------------------------------------------------------------------
// Device-wide exclusive scan of (deg_s[i]-1) -> rp[0..n] (slot space)
// ---------------------------------------------------------------------------
__global__ __launch_bounds__(256) void ppart_k(const int* __restrict__ deg,
                                               int* __restrict__ part, int n) {
    __shared__ int red[256];
    int t = threadIdx.x;
    int i = blockIdx.x * 256 + t;
    red[t] = (i < n) ? deg[i] - 1 : 0;
    __syncthreads();
    for (int off = 128; off; off >>= 1) {
        if (t < off) red[t] += red[t + off];
        __syncthreads();
    }
    if (t == 0) part[blockIdx.x] = red[0];
}

__global__ __launch_bounds__(256) void pscan1_k(int* __restrict__ part, int nb) {
    __shared__ int s[256];
    int t = threadIdx.x;
    s[t] = (t < nb) ? part[t] : 0;
    __syncthreads();
    for (int off = 1; off < 256; off <<= 1) {
        int v = (t >= off) ? s[t - off] : 0;
        __syncthreads();
        s[t] += v;
        __syncthreads();
    }
    if (t < nb) part[t] = (t == 0) ? 0 : s[t - 1];
}

__global__ __launch_bounds__(256) void pwrite_k(const int* __restrict__ deg,
                                                const int* __restrict__ part,
                                                int* __restrict__ rp, int n) {
    __shared__ int s[256];
    int t = threadIdx.x;
    int i = blockIdx.x * 256 + t;
    int val = (i < n) ? deg[i] - 1 : 0;
    s[t] = val;
    __syncthreads();
    for (int off = 1; off < 256; off <<= 1) {
        int v = (t >= off) ? s[t - off] : 0;
        __syncthreads();
        s[t] += v;
        __syncthreads();
    }
    int incl = s[t];
    if (i < n) rp[i] = part[blockIdx.x] + incl - val;
    if (i == n - 1) rp[n] = part[blockIdx.x] + incl;
}

// CSR scatter with renumbering: both endpoints translated to slot space.
__global__ __launch_bounds__(256) void scatter_k(const void* __restrict__ edges,
                                                 const int* __restrict__ flag,
                                                 const int* __restrict__ inv_perm,
                                                 const int* __restrict__ rp,
                                                 int* __restrict__ cursor,
                                                 int* __restrict__ col_s, int e) {
    int i = blockIdx.x * 256 + threadIdx.x;
    if (i < e) {
        int is32 = *flag;
        int r = inv_perm[edge_at(edges, is32, i)];
        int c = inv_perm[edge_at(edges, is32, (long long)NE + i)];
        int pos = rp[r] + atomicAdd(&cursor[r], 1);
        col_s[pos] = c;
    }
}

// ---------------------------------------------------------------------------
// Hadamard: X0 = qe*obj, fp16 hi/lo split, SLOT-MAJOR panels:
// X[panel][slot][32]. Reads original rows via perm (1KB row granularity ->
// full lines), writes sequential.
// ---------------------------------------------------------------------------
__global__ __launch_bounds__(256) void hadamard_k(const float4* __restrict__ a,
                                                  const float4* __restrict__ b,
                                                  const int* __restrict__ perm,
                                                  _Float16* __restrict__ Xh,
                                                  _Float16* __restrict__ Xl, int n4) {
    int i = blockIdx.x * 256 + threadIdx.x;
    if (i >= n4) return;
    int slot = i >> 6;             // 64 float4 per 256-col row
    int q = i & 63;
    int v = perm[slot];
    float4 x = a[(size_t)v * 64 + q], y = b[(size_t)v * 64 + q];
    float vv[4] = { x.x * y.x, x.y * y.y, x.z * y.z, x.w * y.w };
    f16x4 hh, ll;
    #pragma unroll
    for (int j = 0; j < 4; ++j) {
        _Float16 h = (_Float16)vv[j];
        hh[j] = h;
        ll[j] = (_Float16)(vv[j] - (float)h);
    }
    int cq = q * 4;
    size_t off = ((size_t)(cq >> 5) * NN + slot) * 32 + (cq & 31);
    *(f16x4*)&Xh[off] = hh;
    *(f16x4*)&Xl[off] = ll;
}

// ---------------------------------------------------------------------------
// W convert: W[K=256][Nout] fp32 -> B3 [Nout][768] fp16, layout [Wh | Wl | Wh]
// ---------------------------------------------------------------------------
__global__ __launch_bounds__(256) void wconv3_k(const float* __restrict__ W,
                                                _Float16* __restrict__ B3, int Nout) {
    int n = blockIdx.x;            // 0..Nout-1
    int k = threadIdx.x;           // 0..255
    float v = W[(size_t)k * Nout + n];
    _Float16 h = (_Float16)v;
    _Float16 l = (_Float16)(v - (float)h);
    B3[(size_t)n * 768 + k]       = h;
    B3[(size_t)n * 768 + 256 + k] = l;
    B3[(size_t)n * 768 + 512 + k] = h;
}

// ---------------------------------------------------------------------------
// fp16 MFMA GEMM over virtual K=768, slot-major panels in and out.
// Epilogue writes G = dinv_s[row] * (A@W).
// ---------------------------------------------------------------------------
__device__ __forceinline__ void gload_lds16(const void* g, void* l) {
    __builtin_amdgcn_global_load_lds(
        (const __attribute__((address_space(1))) void*)g,
        (__attribute__((address_space(3))) void*)l, 16, 0, 0);
}

template <int NBX, int SW>
__global__ __launch_bounds__(256) void gemm_f16_k(const _Float16* __restrict__ Ah,
                                                  const _Float16* __restrict__ Al,
                                                  const _Float16* __restrict__ B3,
                                                  const float* __restrict__ dinv_s,
                                                  _Float16* __restrict__ C,
                                                  int M, int Nout) {
    __shared__ alignas(16) _Float16 sA[128 * 32];   // linear: row r at r*32, 64B rows
    __shared__ alignas(16) _Float16 sB[128 * 32];
    constexpr int LG = (SW == 32) ? 5 : 4;
    int mblk = (M + 127) >> 7;

    int pair, xb;
    if (NBX == 2) {
        int b = blockIdx.x;
        pair = (b >> 4) * 8 + (b & 7);     // row-panel id; pinned to XCD (b&7)
        xb   = (b >> 3) & 1;
        if (pair >= mblk) return;
    } else {
        pair = blockIdx.x;
        xb = 0;
    }

    int tid = threadIdx.x;
    int row0 = pair * 128, col0 = xb * 128;
    int wid = tid >> 6, lane = tid & 63;
    int wm = wid >> 1, wn = wid & 1;
    int fr = lane & 15;
    int kb = (lane >> 4) * 8;       // k element base within 32

    int sr = lane >> 2;
    int ke = (lane & 3) * 8;

    f32x4 acc[4][4] = {};

    for (int s = 0; s < 24; ++s) {
        int seg = s >> 3;                 // 0: Ah, 1: Ah (L2-hot), 2: Al
        int p = s & 7;                    // A k-panel index
        const _Float16* Asrc = (seg == 2) ? Al : Ah;

        __syncthreads();                  // LDS reuse: prior reads done
        #pragma unroll
        for (int c = 0; c < 2; ++c) {
            int ch = wid * 2 + c;         // 0..7
            int r = ch * 16 + sr;
            int arow = row0 + r;
            if (arow < M)
                gload_lds16(&Asrc[((size_t)p * M + arow) * 32 + ke], &sA[ch * 512]);
            gload_lds16(&B3[(size_t)(col0 + r) * 768 + s * 32 + ke], &sB[ch * 512]);
        }
        __syncthreads();                  // drains vmcnt (global_load_lds) too

        f16x8 af[4];
        #pragma unroll
        for (int f = 0; f < 4; ++f)
            af[f] = *(const f16x8*)&sA[(wm * 64 + f * 16 + fr) * 32 + kb];
        #pragma unroll
        for (int g = 0; g < 4; ++g) {
            f16x8 bf_ = *(const f16x8*)&sB[(wn * 64 + g * 16 + fr) * 32 + kb];
            #pragma unroll
            for (int f = 0; f < 4; ++f)
                acc[f][g] = __builtin_amdgcn_mfma_f32_16x16x32_f16(af[f], bf_, acc[f][g], 0, 0, 0);
        }
    }

    int rsub = (lane >> 4) * 4;
    float dsc[4][4];
    #pragma unroll
    for (int f = 0; f < 4; ++f)
        #pragma unroll
        for (int r = 0; r < 4; ++r) {
            int row = row0 + wm * 64 + f * 16 + rsub + r;
            dsc[f][r] = (row < M) ? dinv_s[row] : 0.0f;
        }
    #pragma unroll
    for (int f = 0; f < 4; ++f) {
        #pragma unroll
        for (int g = 0; g < 4; ++g) {
            int col = col0 + wn * 64 + g * 16 + fr;
            #pragma unroll
            for (int r = 0; r < 4; ++r) {
                int row = row0 + wm * 64 + f * 16 + rsub + r;
                if (row < M)
                    C[((size_t)(col >> LG) * M + row) * SW + (col & (SW - 1))] =
                        (_Float16)(acc[f][g][r] * dsc[f][r]);
            }
        }
    }
}

// ---------------------------------------------------------------------------
// XCD-sliced aggregation v7: fully slot-space. Sequential self-reads, rp/cs
// walks, and Y writes (no perm lookups, no write-allocate scatter tax);
// waves process equal-degree slots (slots are degree-sorted).
// MODE 0: relu, slot-major fp16 hi/lo out. MODE 1: fp32 scatter to orig rows
// (512B/node = whole lines).
// ---------------------------------------------------------------------------
template <int D, int MODE>
__global__ __launch_bounds__(256) void aggregate_slice_k(const _Float16* __restrict__ G,
                                                         const float* __restrict__ bias,
                                                         const float* __restrict__ dinv_s,
                                                         const int* __restrict__ rp,
                                                         const int* __restrict__ cs,
                                                         const int* __restrict__ perm,
                                                         _Float16* __restrict__ Yh,
                                                         _Float16* __restrict__ Yl,
                                                         float* __restrict__ Yf, int n) {
    constexpr int SLICE = (D == 256) ? 32 : 16;   // panel width
    constexpr int LPN = SLICE / 8;                // lanes per node (f16x8 each)
    constexpr int NPB = 256 / LPN;                // nodes per block

    int bid = blockIdx.x;
    int s = bid & 7;
    int slot = (bid >> 3) * NPB + threadIdx.x / LPN;
    if (slot >= n) return;
    int sub = threadIdx.x % LPN;
    int co = sub * 8;                             // within-panel col offset
    int col = s * SLICE + co;                     // global col (bias / out)

    const _Float16* Gs = G + (size_t)s * n * SLICE;   // this slice's panel

    float acc[8];
    {
        f16x8 t0 = *(const f16x8*)&Gs[(size_t)slot * SLICE + co];
        #pragma unroll
        for (int i = 0; i < 8; ++i) acc[i] = (float)t0[i];
    }

    int beg = rp[slot], end = rp[slot + 1];
    int j = beg;
    for (; j + 8 <= end; j += 8) {
        int cc[8];
        #pragma unroll
        for (int u = 0; u < 8; ++u) cc[u] = cs[j + u];
        f16x8 hv[8];
        #pragma unroll
        for (int u = 0; u < 8; ++u)
            hv[u] = *(const f16x8*)&Gs[(size_t)cc[u] * SLICE + co];
        #pragma unroll
        for (int u = 0; u < 8; ++u)
            #pragma unroll
            for (int i = 0; i < 8; ++i)
                acc[i] += (float)hv[u][i];
    }
    for (; j < end; ++j) {
        int c = cs[j];
        f16x8 a = *(const f16x8*)&Gs[(size_t)c * SLICE + co];
        #pragma unroll
        for (int i = 0; i < 8; ++i) acc[i] += (float)a[i];
    }

    float dv = dinv_s[slot];
    float4 b0 = *(const float4*)&bias[col];
    float4 b1 = *(const float4*)&bias[col + 4];
    float bb[8] = { b0.x, b0.y, b0.z, b0.w, b1.x, b1.y, b1.z, b1.w };

    if constexpr (MODE == 0) {
        f16x8 hh, ll;
        #pragma unroll
        for (int i = 0; i < 8; ++i) {
            float o = fmaxf(dv * acc[i] + bb[i], 0.0f);
            _Float16 h = (_Float16)o;
            hh[i] = h;
            ll[i] = (_Float16)(o - (float)h);
        }
        size_t off = ((size_t)s * n + slot) * SLICE + co;   // slot-major out
        *(f16x8*)&Yh[off] = hh;
        *(f16x8*)&Yl[off] = ll;
    } else {
        int v = perm[slot];                                 // orig node id
        float o[8];
        #pragma unroll
        for (int i = 0; i < 8; ++i) o[i] = dv * acc[i] + bb[i];
        *(float4*)&Yf[(size_t)v * D + col]     = make_float4(o[0], o[1], o[2], o[3]);
        *(float4*)&Yf[(size_t)v * D + col + 4] = make_float4(o[4], o[5], o[6], o[7]);
    }
}

// ---------------------------------------------------------------------------
extern "C" void kernel_launch(void* const* d_in, const int* in_sizes, int n_in,
                              void* d_out, int out_size, void* d_ws, size_t ws_size,
                              hipStream_t stream) {
    const float* qe  = (const float*)d_in[0];
    const float* obj = (const float*)d_in[1];
    const void*  edges = d_in[2];
    const float* W1 = (const float*)d_in[3];
    const float* b1 = (const float*)d_in[4];
    const float* W2 = (const float*)d_in[5];
    const float* b2 = (const float*)d_in[6];
    const float* W3 = (const float*)d_in[7];
    const float* b3 = (const float*)d_in[8];
    float* out = (float*)d_out;

    char* p = (char*)d_ws;
    _Float16* Xh   = (_Float16*)p; p += (size_t)NN * 256 * 2;   // 25.6 MB (slot-major)
    _Float16* Xl   = (_Float16*)p; p += (size_t)NN * 256 * 2;   // 25.6 MB (slot-major)
    _Float16* H    = (_Float16*)p; p += (size_t)NN * 256 * 2;   // 25.6 MB (slot-major G)
    _Float16* B3   = (_Float16*)p; p += (size_t)256 * 768 * 2;  // 0.4 MB
    int*   deg     = (int*)p;   p += (size_t)NN * 4;
    int*   deg_s   = (int*)p;   p += (size_t)NN * 4;
    float* dinv_s  = (float*)p; p += (size_t)NN * 4;
    int*   rp      = (int*)p;   p += (size_t)(NN + 1) * 4;
    int*   cursor  = (int*)p;   p += (size_t)NN * 4;
    int*   col_s   = (int*)p;   p += (size_t)NE * 4;
    int*   bh      = (int*)p;   p += (size_t)NBLK * 1024 * 4;   // 0.8 MB
    int*   tot     = (int*)p;   p += 1024 * 4;
    int*   bstart  = (int*)p;   p += 1024 * 4;
    int*   part    = (int*)p;   p += NBLK * 4;
    int*   perm    = (int*)p;   p += (size_t)NN * 4;
    int*   inv_perm= (int*)p;   p += (size_t)NN * 4;
    int*   flag    = (int*)p;   p += 4;

    zero_flag_k<<<1, 64, 0, stream>>>(flag);
    detect_k<<<4, 256, 0, stream>>>((const int*)edges, flag);
    init_k<<<(NN + 255) / 256, 256, 0, stream>>>(deg, cursor, NN);
    count_k<<<(NE + 255) / 256, 256, 0, stream>>>(edges, flag, deg, NE);
    // degree-sorted renumbering
    bh_k<<<NBLK, 256, 0, stream>>>(deg, bh, NN);
    btot_k<<<1024, 256, 0, stream>>>(bh, tot, NBLK);
    hscan_k<<<1, 1024, 0, stream>>>(tot, bstart);
    bbase_k<<<1024, 256, 0, stream>>>(bh, bstart, NBLK);
    pscatter_k<<<NBLK, 256, 0, stream>>>(deg, bh, perm, inv_perm, NN);
    degs_k<<<NBLK, 256, 0, stream>>>(deg, perm, deg_s, dinv_s, NN);
    // rp over slot-space degrees
    ppart_k<<<NBLK, 256, 0, stream>>>(deg_s, part, NN);
    pscan1_k<<<1, 256, 0, stream>>>(part, NBLK);
    pwrite_k<<<NBLK, 256, 0, stream>>>(deg_s, part, rp, NN);
    // translated CSR
    scatter_k<<<(NE + 255) / 256, 256, 0, stream>>>(edges, flag, inv_perm, rp, cursor,
                                                    col_s, NE);
    // slot-major X0
    hadamard_k<<<(NN * 64 + 255) / 256, 256, 0, stream>>>(
        (const float4*)qe, (const float4*)obj, perm, Xh, Xl, NN * 64);

    int mblk = (NN + 127) / 128;                 // 391
    int gemmBigGrid = ((mblk + 7) / 8) * 16;     // 800 (pair-swizzled, 2 col blocks)
    int agg256Grid = ((NN + 63) / 64) * 8;       // 6256  (64 nodes/block, 4 lanes/node)
    int agg128Grid = ((NN + 127) / 128) * 8;     // 3128  (128 nodes/block, 2 lanes/node)

    // Layer 1
    wconv3_k<<<256, 256, 0, stream>>>(W1, B3, 256);
    gemm_f16_k<2, 32><<<gemmBigGrid, 256, 0, stream>>>(Xh, Xl, B3, dinv_s, H, NN, 256);
    aggregate_slice_k<256, 0><<<agg256Grid, 256, 0, stream>>>(H, b1, dinv_s, rp, col_s, perm,
                                                              Xh, Xl, nullptr, NN);
    // Layer 2
    wconv3_k<<<256, 256, 0, stream>>>(W2, B3, 256);
    gemm_f16_k<2, 32><<<gemmBigGrid, 256, 0, stream>>>(Xh, Xl, B3, dinv_s, H, NN, 256);
    aggregate_slice_k<256, 0><<<agg256Grid, 256, 0, stream>>>(H, b2, dinv_s, rp, col_s, perm,
                                                              Xh, Xl, nullptr, NN);
    // Layer 3
    wconv3_k<<<128, 256, 0, stream>>>(W3, B3, 128);
    gemm_f16_k<1, 16><<<mblk, 256, 0, stream>>>(Xh, Xl, B3, dinv_s, H, NN, 128);
    aggregate_slice_k<128, 1><<<agg128Grid, 256, 0, stream>>>(H, b3, dinv_s, rp, col_s, perm,
                                                              nullptr, nullptr, out, NN);
}

// Round 12
// 401.467 us; speedup vs baseline: 1.9708x; 1.0045x over previous
//
#include <hip/hip_runtime.h>
#include <cstdint>
#include <cstddef>

#define NN 50000
#define NE 800000
#define NBLK ((NN + 255) / 256)   // 196 node-chunks

typedef _Float16 f16x8 __attribute__((ext_vector_type(8)));
typedef _Float16 f16x4 __attribute__((ext_vector_type(4)));
typedef float f32x4 __attribute__((ext_vector_type(4)));

// ---------------------------------------------------------------------------
// Edge-index dtype robustness (int64 vs int32 canonicalization)
// ---------------------------------------------------------------------------
__device__ __forceinline__ int edge_at(const void* e, int is32, long long i) {
    return is32 ? ((const int*)e)[i] : (int)((const long long*)e)[i];
}

__global__ __launch_bounds__(64) void zero_flag_k(int* flag) {
    if (threadIdx.x == 0) *flag = 0;
}

__global__ __launch_bounds__(256) void detect_k(const int* __restrict__ w, int* __restrict__ flag) {
    int i = blockIdx.x * 256 + threadIdx.x;   // 0..1023
    if (i < 1024 && w[2 * i + 1] != 0) atomicOr(flag, 1);
}

// ---------------------------------------------------------------------------
// Degree count (original node ids)
// ---------------------------------------------------------------------------
__global__ __launch_bounds__(256) void init_k(int* __restrict__ deg, int* __restrict__ cursor, int n) {
    int i = blockIdx.x * 256 + threadIdx.x;
    if (i < n) { deg[i] = 1; cursor[i] = 0; }   // self-loop
}

__global__ __launch_bounds__(256) void count_k(const void* __restrict__ edges,
                                               const int* __restrict__ flag,
                                               int* __restrict__ deg, int e) {
    int i = blockIdx.x * 256 + threadIdx.x;
    if (i < e) {
        int is32 = *flag;
        atomicAdd(&deg[edge_at(edges, is32, i)], 1);
    }
}

// ---------------------------------------------------------------------------
// Degree-sorted node permutation, contention-free 3-phase counting sort.
// Produces perm (slot->orig) AND inv_perm (orig->slot): full graph renumber.
// ---------------------------------------------------------------------------
__global__ __launch_bounds__(256) void bh_k(const int* __restrict__ deg,
                                            int* __restrict__ bh, int n) {
    __shared__ int lh[1024];
    int t = threadIdx.x;
    for (int b = t; b < 1024; b += 256) lh[b] = 0;
    __syncthreads();
    int i = blockIdx.x * 256 + t;
    if (i < n) atomicAdd(&lh[min(deg[i], 1023)], 1);
    __syncthreads();
    for (int b = t; b < 1024; b += 256) bh[(size_t)blockIdx.x * 1024 + b] = lh[b];
}

__global__ __launch_bounds__(256) void btot_k(const int* __restrict__ bh,
                                              int* __restrict__ tot, int nb) {
    __shared__ int red[256];
    int b = blockIdx.x, t = threadIdx.x;
    int s = 0;
    for (int blk = t; blk < nb; blk += 256) s += bh[(size_t)blk * 1024 + b];
    red[t] = s;
    __syncthreads();
    for (int off = 128; off; off >>= 1) {
        if (t < off) red[t] += red[t + off];
        __syncthreads();
    }
    if (t == 0) tot[b] = red[0];
}

__global__ __launch_bounds__(1024) void hscan_k(const int* __restrict__ hist,
                                                int* __restrict__ bcur) {
    __shared__ int s[1024];
    int t = threadIdx.x;
    s[t] = hist[t];
    __syncthreads();
    for (int off = 1; off < 1024; off <<= 1) {
        int val = (t >= off) ? s[t - off] : 0;
        __syncthreads();
        s[t] += val;
        __syncthreads();
    }
    bcur[t] = (t == 0) ? 0 : s[t - 1];
}

__global__ __launch_bounds__(256) void bbase_k(int* __restrict__ bh,
                                               const int* __restrict__ bstart, int nb) {
    __shared__ int s[256];
    int b = blockIdx.x, t = threadIdx.x;
    int v = (t < nb) ? bh[(size_t)t * 1024 + b] : 0;
    s[t] = v;
    __syncthreads();
    for (int off = 1; off < 256; off <<= 1) {
        int x = (t >= off) ? s[t - off] : 0;
        __syncthreads();
        s[t] += x;
        __syncthreads();
    }
    int excl = (t == 0) ? 0 : s[t - 1];
    if (t < nb) bh[(size_t)t * 1024 + b] = bstart[b] + excl;
}

__global__ __launch_bounds__(256) void pscatter_k(const int* __restrict__ deg,
                                                  const int* __restrict__ bh,
                                                  int* __restrict__ perm,
                                                  int* __restrict__ inv_perm, int n) {
    __shared__ int lh[1024];
    int t = threadIdx.x;
    for (int b = t; b < 1024; b += 256) lh[b] = 0;
    __syncthreads();
    int i = blockIdx.x * 256 + t;
    int b = 0, r = 0;
    if (i < n) {
        b = min(deg[i], 1023);
        r = atomicAdd(&lh[b], 1);
    }
    __syncthreads();
    if (i < n) {
        int pos = bh[(size_t)blockIdx.x * 1024 + b] + r;
        perm[pos] = i;
        inv_perm[i] = pos;
    }
}

// slot-space degree + dinv
__global__ __launch_bounds__(256) void degs_k(const int* __restrict__ deg,
                                              const int* __restrict__ perm,
                                              int* __restrict__ deg_s,
                                              float* __restrict__ dinv_s, int n) {
    int i = blockIdx.x * 256 + threadIdx.x;
    if (i < n) {
        int d = deg[perm[i]];
        deg_s[i] = d;
        dinv_s[i] = rsqrtf((float)d);
    }
}

// ---------------------------------------------------------------------------
// Device-wide exclusive scan of (deg_s[i]-1) -> rp[0..n] (slot space)
// ---------------------------------------------------------------------------
__global__ __launch_bounds__(256) void ppart_k(const int* __restrict__ deg,
                                               int* __restrict__ part, int n) {
    __shared__ int red[256];
    int t = threadIdx.x;
    int i = blockIdx.x * 256 + t;
    red[t] = (i < n) ? deg[i] - 1 : 0;
    __syncthreads();
    for (int off = 128; off; off >>= 1) {
        if (t < off) red[t] += red[t + off];
        __syncthreads();
    }
    if (t == 0) part[blockIdx.x] = red[0];
}

__global__ __launch_bounds__(256) void pscan1_k(int* __restrict__ part, int nb) {
    __shared__ int s[256];
    int t = threadIdx.x;
    s[t] = (t < nb) ? part[t] : 0;
    __syncthreads();
    for (int off = 1; off < 256; off <<= 1) {
        int v = (t >= off) ? s[t - off] : 0;
        __syncthreads();
        s[t] += v;
        __syncthreads();
    }
    if (t < nb) part[t] = (t == 0) ? 0 : s[t - 1];
}

__global__ __launch_bounds__(256) void pwrite_k(const int* __restrict__ deg,
                                                const int* __restrict__ part,
                                                int* __restrict__ rp, int n) {
    __shared__ int s[256];
    int t = threadIdx.x;
    int i = blockIdx.x * 256 + t;
    int val = (i < n) ? deg[i] - 1 : 0;
    s[t] = val;
    __syncthreads();
    for (int off = 1; off < 256; off <<= 1) {
        int v = (t >= off) ? s[t - off] : 0;
        __syncthreads();
        s[t] += v;
        __syncthreads();
    }
    int incl = s[t];
    if (i < n) rp[i] = part[blockIdx.x] + incl - val;
    if (i == n - 1) rp[n] = part[blockIdx.x] + incl;
}

// CSR scatter with renumbering: both endpoints translated to slot space.
__global__ __launch_bounds__(256) void scatter_k(const void* __restrict__ edges,
                                                 const int* __restrict__ flag,
                                                 const int* __restrict__ inv_perm,
                                                 const int* __restrict__ rp,
                                                 int* __restrict__ cursor,
                                                 int* __restrict__ col_s, int e) {
    int i = blockIdx.x * 256 + threadIdx.x;
    if (i < e) {
        int is32 = *flag;
        int r = inv_perm[edge_at(edges, is32, i)];
        int c = inv_perm[edge_at(edges, is32, (long long)NE + i)];
        int pos = rp[r] + atomicAdd(&cursor[r], 1);
        col_s[pos] = c;
    }
}

// ---------------------------------------------------------------------------
// Hadamard: X0 = qe*obj, fp16 hi/lo split, SLOT-MAJOR panels:
// X[panel][slot][32]. Reads original rows via perm, writes sequential.
// ---------------------------------------------------------------------------
__global__ __launch_bounds__(256) void hadamard_k(const float4* __restrict__ a,
                                                  const float4* __restrict__ b,
                                                  const int* __restrict__ perm,
                                                  _Float16* __restrict__ Xh,
                                                  _Float16* __restrict__ Xl, int n4) {
    int i = blockIdx.x * 256 + threadIdx.x;
    if (i >= n4) return;
    int slot = i >> 6;             // 64 float4 per 256-col row
    int q = i & 63;
    int v = perm[slot];
    float4 x = a[(size_t)v * 64 + q], y = b[(size_t)v * 64 + q];
    float vv[4] = { x.x * y.x, x.y * y.y, x.z * y.z, x.w * y.w };
    f16x4 hh, ll;
    #pragma unroll
    for (int j = 0; j < 4; ++j) {
        _Float16 h = (_Float16)vv[j];
        hh[j] = h;
        ll[j] = (_Float16)(vv[j] - (float)h);
    }
    int cq = q * 4;
    size_t off = ((size_t)(cq >> 5) * NN + slot) * 32 + (cq & 31);
    *(f16x4*)&Xh[off] = hh;
    *(f16x4*)&Xl[off] = ll;
}

// ---------------------------------------------------------------------------
// W convert: W[K=256][Nout] fp32 -> B3 [Nout][768] fp16, layout [Wh | Wl | Wh]
// ---------------------------------------------------------------------------
__global__ __launch_bounds__(256) void wconv3_k(const float* __restrict__ W,
                                                _Float16* __restrict__ B3, int Nout) {
    int n = blockIdx.x;            // 0..Nout-1
    int k = threadIdx.x;           // 0..255
    float v = W[(size_t)k * Nout + n];
    _Float16 h = (_Float16)v;
    _Float16 l = (_Float16)(v - (float)h);
    B3[(size_t)n * 768 + k]       = h;
    B3[(size_t)n * 768 + 256 + k] = l;
    B3[(size_t)n * 768 + 512 + k] = h;
}

// ---------------------------------------------------------------------------
// fp16 MFMA GEMM over virtual K=768, slot-major panels in and out.
// LDS XOR-swizzle (rule #21: linear gload_lds dest + pre-swizzled global
// SOURCE + same XOR on the READ): 16B chunk c within each 64B LDS row is
// stored/read at c ^ ((row>>1)&3). Read walk: rows base+0..15 at fixed k
// spread over 2 bank-halves x 4 chunk slots = 2 lanes/bank-group (free),
// was 8-way (2.4M conflicts/dispatch at r11).
// Epilogue writes G = dinv_s[row] * (A@W).
// ---------------------------------------------------------------------------
__device__ __forceinline__ void gload_lds16(const void* g, void* l) {
    __builtin_amdgcn_global_load_lds(
        (const __attribute__((address_space(1))) void*)g,
        (__attribute__((address_space(3))) void*)l, 16, 0, 0);
}

template <int NBX, int SW>
__global__ __launch_bounds__(256) void gemm_f16_k(const _Float16* __restrict__ Ah,
                                                  const _Float16* __restrict__ Al,
                                                  const _Float16* __restrict__ B3,
                                                  const float* __restrict__ dinv_s,
                                                  _Float16* __restrict__ C,
                                                  int M, int Nout) {
    __shared__ alignas(16) _Float16 sA[128 * 32];   // linear: row r at r*32, 64B rows
    __shared__ alignas(16) _Float16 sB[128 * 32];
    constexpr int LG = (SW == 32) ? 5 : 4;
    int mblk = (M + 127) >> 7;

    int pair, xb;
    if (NBX == 2) {
        int b = blockIdx.x;
        pair = (b >> 4) * 8 + (b & 7);     // row-panel id; pinned to XCD (b&7)
        xb   = (b >> 3) & 1;
        if (pair >= mblk) return;
    } else {
        pair = blockIdx.x;
        xb = 0;
    }

    int tid = threadIdx.x;
    int row0 = pair * 128, col0 = xb * 128;
    int wid = tid >> 6, lane = tid & 63;
    int wm = wid >> 1, wn = wid & 1;
    int fr = lane & 15;
    int kbc = lane >> 4;            // k chunk index 0..3 (8 fp16 each)

    int sr = lane >> 2;             // staging row within 16-row chunk
    // pre-swizzled global source chunk: lane's LDS slot (lane&3) holds
    // global chunk (lane&3) ^ ((sr>>1)&3)
    int ke = (((lane & 3) ^ ((sr >> 1) & 3)) * 8);

    f32x4 acc[4][4] = {};

    for (int s = 0; s < 24; ++s) {
        int seg = s >> 3;                 // 0: Ah, 1: Ah (L2-hot), 2: Al
        int p = s & 7;                    // A k-panel index
        const _Float16* Asrc = (seg == 2) ? Al : Ah;

        __syncthreads();                  // LDS reuse: prior reads done
        #pragma unroll
        for (int c = 0; c < 2; ++c) {
            int ch = wid * 2 + c;         // 0..7
            int r = ch * 16 + sr;
            int arow = row0 + r;
            if (arow < M)
                gload_lds16(&Asrc[((size_t)p * M + arow) * 32 + ke], &sA[ch * 512]);
            gload_lds16(&B3[(size_t)(col0 + r) * 768 + s * 32 + ke], &sB[ch * 512]);
        }
        __syncthreads();                  // drains vmcnt (global_load_lds) too

        f16x8 af[4];
        #pragma unroll
        for (int f = 0; f < 4; ++f) {
            int rr = wm * 64 + f * 16 + fr;
            af[f] = *(const f16x8*)&sA[rr * 32 + ((kbc ^ ((rr >> 1) & 3)) * 8)];
        }
        #pragma unroll
        for (int g = 0; g < 4; ++g) {
            int cc = wn * 64 + g * 16 + fr;
            f16x8 bf_ = *(const f16x8*)&sB[cc * 32 + ((kbc ^ ((cc >> 1) & 3)) * 8)];
            #pragma unroll
            for (int f = 0; f < 4; ++f)
                acc[f][g] = __builtin_amdgcn_mfma_f32_16x16x32_f16(af[f], bf_, acc[f][g], 0, 0, 0);
        }
    }

    int rsub = (lane >> 4) * 4;
    float dsc[4][4];
    #pragma unroll
    for (int f = 0; f < 4; ++f)
        #pragma unroll
        for (int r = 0; r < 4; ++r) {
            int row = row0 + wm * 64 + f * 16 + rsub + r;
            dsc[f][r] = (row < M) ? dinv_s[row] : 0.0f;
        }
    #pragma unroll
    for (int f = 0; f < 4; ++f) {
        #pragma unroll
        for (int g = 0; g < 4; ++g) {
            int col = col0 + wn * 64 + g * 16 + fr;
            #pragma unroll
            for (int r = 0; r < 4; ++r) {
                int row = row0 + wm * 64 + f * 16 + rsub + r;
                if (row < M)
                    C[((size_t)(col >> LG) * M + row) * SW + (col & (SW - 1))] =
                        (_Float16)(acc[f][g][r] * dsc[f][r]);
            }
        }
    }
}

// ---------------------------------------------------------------------------
// XCD-sliced aggregation v7: fully slot-space. Sequential self-reads, rp/cs
// walks, and Y writes; waves process equal-degree slots.
// MODE 0: relu, slot-major fp16 hi/lo out. MODE 1: fp32 scatter to orig rows.
// ---------------------------------------------------------------------------
template <int D, int MODE>
__global__ __launch_bounds__(256) void aggregate_slice_k(const _Float16* __restrict__ G,
                                                         const float* __restrict__ bias,
                                                         const float* __restrict__ dinv_s,
                                                         const int* __restrict__ rp,
                                                         const int* __restrict__ cs,
                                                         const int* __restrict__ perm,
                                                         _Float16* __restrict__ Yh,
                                                         _Float16* __restrict__ Yl,
                                                         float* __restrict__ Yf, int n) {
    constexpr int SLICE = (D == 256) ? 32 : 16;   // panel width
    constexpr int LPN = SLICE / 8;                // lanes per node (f16x8 each)
    constexpr int NPB = 256 / LPN;                // nodes per block

    int bid = blockIdx.x;
    int s = bid & 7;
    int slot = (bid >> 3) * NPB + threadIdx.x / LPN;
    if (slot >= n) return;
    int sub = threadIdx.x % LPN;
    int co = sub * 8;                             // within-panel col offset
    int col = s * SLICE + co;                     // global col (bias / out)

    const _Float16* Gs = G + (size_t)s * n * SLICE;   // this slice's panel

    float acc[8];
    {
        f16x8 t0 = *(const f16x8*)&Gs[(size_t)slot * SLICE + co];
        #pragma unroll
        for (int i = 0; i < 8; ++i) acc[i] = (float)t0[i];
    }

    int beg = rp[slot], end = rp[slot + 1];
    int j = beg;
    for (; j + 8 <= end; j += 8) {
        int cc[8];
        #pragma unroll
        for (int u = 0; u < 8; ++u) cc[u] = cs[j + u];
        f16x8 hv[8];
        #pragma unroll
        for (int u = 0; u < 8; ++u)
            hv[u] = *(const f16x8*)&Gs[(size_t)cc[u] * SLICE + co];
        #pragma unroll
        for (int u = 0; u < 8; ++u)
            #pragma unroll
            for (int i = 0; i < 8; ++i)
                acc[i] += (float)hv[u][i];
    }
    for (; j < end; ++j) {
        int c = cs[j];
        f16x8 a = *(const f16x8*)&Gs[(size_t)c * SLICE + co];
        #pragma unroll
        for (int i = 0; i < 8; ++i) acc[i] += (float)a[i];
    }

    float dv = dinv_s[slot];
    float4 b0 = *(const float4*)&bias[col];
    float4 b1 = *(const float4*)&bias[col + 4];
    float bb[8] = { b0.x, b0.y, b0.z, b0.w, b1.x, b1.y, b1.z, b1.w };

    if constexpr (MODE == 0) {
        f16x8 hh, ll;
        #pragma unroll
        for (int i = 0; i < 8; ++i) {
            float o = fmaxf(dv * acc[i] + bb[i], 0.0f);
            _Float16 h = (_Float16)o;
            hh[i] = h;
            ll[i] = (_Float16)(o - (float)h);
        }
        size_t off = ((size_t)s * n + slot) * SLICE + co;   // slot-major out
        *(f16x8*)&Yh[off] = hh;
        *(f16x8*)&Yl[off] = ll;
    } else {
        int v = perm[slot];                                 // orig node id
        float o[8];
        #pragma unroll
        for (int i = 0; i < 8; ++i) o[i] = dv * acc[i] + bb[i];
        *(float4*)&Yf[(size_t)v * D + col]     = make_float4(o[0], o[1], o[2], o[3]);
        *(float4*)&Yf[(size_t)v * D + col + 4] = make_float4(o[4], o[5], o[6], o[7]);
    }
}

// ---------------------------------------------------------------------------
extern "C" void kernel_launch(void* const* d_in, const int* in_sizes, int n_in,
                              void* d_out, int out_size, void* d_ws, size_t ws_size,
                              hipStream_t stream) {
    const float* qe  = (const float*)d_in[0];
    const float* obj = (const float*)d_in[1];
    const void*  edges = d_in[2];
    const float* W1 = (const float*)d_in[3];
    const float* b1 = (const float*)d_in[4];
    const float* W2 = (const float*)d_in[5];
    const float* b2 = (const float*)d_in[6];
    const float* W3 = (const float*)d_in[7];
    const float* b3 = (const float*)d_in[8];
    float* out = (float*)d_out;

    char* p = (char*)d_ws;
    _Float16* Xh   = (_Float16*)p; p += (size_t)NN * 256 * 2;   // 25.6 MB (slot-major)
    _Float16* Xl   = (_Float16*)p; p += (size_t)NN * 256 * 2;   // 25.6 MB (slot-major)
    _Float16* H    = (_Float16*)p; p += (size_t)NN * 256 * 2;   // 25.6 MB (slot-major G)
    _Float16* B3   = (_Float16*)p; p += (size_t)256 * 768 * 2;  // 0.4 MB
    int*   deg     = (int*)p;   p += (size_t)NN * 4;
    int*   deg_s   = (int*)p;   p += (size_t)NN * 4;
    float* dinv_s  = (float*)p; p += (size_t)NN * 4;
    int*   rp      = (int*)p;   p += (size_t)(NN + 1) * 4;
    int*   cursor  = (int*)p;   p += (size_t)NN * 4;
    int*   col_s   = (int*)p;   p += (size_t)NE * 4;
    int*   bh      = (int*)p;   p += (size_t)NBLK * 1024 * 4;   // 0.8 MB
    int*   tot     = (int*)p;   p += 1024 * 4;
    int*   bstart  = (int*)p;   p += 1024 * 4;
    int*   part    = (int*)p;   p += NBLK * 4;
    int*   perm    = (int*)p;   p += (size_t)NN * 4;
    int*   inv_perm= (int*)p;   p += (size_t)NN * 4;
    int*   flag    = (int*)p;   p += 4;

    zero_flag_k<<<1, 64, 0, stream>>>(flag);
    detect_k<<<4, 256, 0, stream>>>((const int*)edges, flag);
    init_k<<<(NN + 255) / 256, 256, 0, stream>>>(deg, cursor, NN);
    count_k<<<(NE + 255) / 256, 256, 0, stream>>>(edges, flag, deg, NE);
    // degree-sorted renumbering
    bh_k<<<NBLK, 256, 0, stream>>>(deg, bh, NN);
    btot_k<<<1024, 256, 0, stream>>>(bh, tot, NBLK);
    hscan_k<<<1, 1024, 0, stream>>>(tot, bstart);
    bbase_k<<<1024, 256, 0, stream>>>(bh, bstart, NBLK);
    pscatter_k<<<NBLK, 256, 0, stream>>>(deg, bh, perm, inv_perm, NN);
    degs_k<<<NBLK, 256, 0, stream>>>(deg, perm, deg_s, dinv_s, NN);
    // rp over slot-space degrees
    ppart_k<<<NBLK, 256, 0, stream>>>(deg_s, part, NN);
    pscan1_k<<<1, 256, 0, stream>>>(part, NBLK);
    pwrite_k<<<NBLK, 256, 0, stream>>>(deg_s, part, rp, NN);
    // translated CSR
    scatter_k<<<(NE + 255) / 256, 256, 0, stream>>>(edges, flag, inv_perm, rp, cursor,
                                                    col_s, NE);
    // slot-major X0
    hadamard_k<<<(NN * 64 + 255) / 256, 256, 0, stream>>>(
        (const float4*)qe, (const float4*)obj, perm, Xh, Xl, NN * 64);

    int mblk = (NN + 127) / 128;                 // 391
    int gemmBigGrid = ((mblk + 7) / 8) * 16;     // 800 (pair-swizzled, 2 col blocks)
    int agg256Grid = ((NN + 63) / 64) * 8;       // 6256  (64 nodes/block, 4 lanes/node)
    int agg128Grid = ((NN + 127) / 128) * 8;     // 3128  (128 nodes/block, 2 lanes/node)

    // Layer 1
    wconv3_k<<<256, 256, 0, stream>>>(W1, B3, 256);
    gemm_f16_k<2, 32><<<gemmBigGrid, 256, 0, stream>>>(Xh, Xl, B3, dinv_s, H, NN, 256);
    aggregate_slice_k<256, 0><<<agg256Grid, 256, 0, stream>>>(H, b1, dinv_s, rp, col_s, perm,
                                                              Xh, Xl, nullptr, NN);
    // Layer 2
    wconv3_k<<<256, 256, 0, stream>>>(W2, B3, 256);
    gemm_f16_k<2, 32><<<gemmBigGrid, 256, 0, stream>>>(Xh, Xl, B3, dinv_s, H, NN, 256);
    aggregate_slice_k<256, 0><<<agg256Grid, 256, 0, stream>>>(H, b2, dinv_s, rp, col_s, perm,
                                                              Xh, Xl, nullptr, NN);
    // Layer 3
    wconv3_k<<<128, 256, 0, stream>>>(W3, B3, 128);
    gemm_f16_k<1, 16><<<mblk, 256, 0, stream>>>(Xh, Xl, B3, dinv_s, H, NN, 128);
    aggregate_slice_k<128, 1><<<agg128Grid, 256, 0, stream>>>(H, b3, dinv_s, rp, col_s, perm,
                                                              nullptr, nullptr, out, NN);
}

// Round 13
// 356.470 us; speedup vs baseline: 2.2195x; 1.1262x over previous
//
#include <hip/hip_runtime.h>
#include <cstdint>
#include <cstddef>

#define NN 50000
#define NE 800000
#define NBLK ((NN + 255) / 256)   // 196 node-chunks

typedef _Float16 f16x8 __attribute__((ext_vector_type(8)));
typedef _Float16 f16x4 __attribute__((ext_vector_type(4)));
typedef float f32x4 __attribute__((ext_vector_type(4)));

// ---------------------------------------------------------------------------
// Edge-index dtype robustness (int64 vs int32 canonicalization)
// ---------------------------------------------------------------------------
__device__ __forceinline__ int edge_at(const void* e, int is32, long long i) {
    return is32 ? ((const int*)e)[i] : (int)((const long long*)e)[i];
}

__global__ __launch_bounds__(64) void zero_flag_k(int* flag) {
    if (threadIdx.x == 0) *flag = 0;
}

__global__ __launch_bounds__(256) void detect_k(const int* __restrict__ w, int* __restrict__ flag) {
    int i = blockIdx.x * 256 + threadIdx.x;   // 0..1023
    if (i < 1024 && w[2 * i + 1] != 0) atomicOr(flag, 1);
}

// ---------------------------------------------------------------------------
// Degree count (original node ids)
// ---------------------------------------------------------------------------
__global__ __launch_bounds__(256) void init_k(int* __restrict__ deg, int* __restrict__ cursor, int n) {
    int i = blockIdx.x * 256 + threadIdx.x;
    if (i < n) { deg[i] = 1; cursor[i] = 0; }   // self-loop
}

__global__ __launch_bounds__(256) void count_k(const void* __restrict__ edges,
                                               const int* __restrict__ flag,
                                               int* __restrict__ deg, int e) {
    int i = blockIdx.x * 256 + threadIdx.x;
    if (i < e) {
        int is32 = *flag;
        atomicAdd(&deg[edge_at(edges, is32, i)], 1);
    }
}

// ---------------------------------------------------------------------------
// Degree-sorted node permutation, contention-free 3-phase counting sort.
// ---------------------------------------------------------------------------
__global__ __launch_bounds__(256) void bh_k(const int* __restrict__ deg,
                                            int* __restrict__ bh, int n) {
    __shared__ int lh[1024];
    int t = threadIdx.x;
    for (int b = t; b < 1024; b += 256) lh[b] = 0;
    __syncthreads();
    int i = blockIdx.x * 256 + t;
    if (i < n) atomicAdd(&lh[min(deg[i], 1023)], 1);
    __syncthreads();
    for (int b = t; b < 1024; b += 256) bh[(size_t)blockIdx.x * 1024 + b] = lh[b];
}

__global__ __launch_bounds__(256) void btot_k(const int* __restrict__ bh,
                                              int* __restrict__ tot, int nb) {
    __shared__ int red[256];
    int b = blockIdx.x, t = threadIdx.x;
    int s = 0;
    for (int blk = t; blk < nb; blk += 256) s += bh[(size_t)blk * 1024 + b];
    red[t] = s;
    __syncthreads();
    for (int off = 128; off; off >>= 1) {
        if (t < off) red[t] += red[t + off];
        __syncthreads();
    }
    if (t == 0) tot[b] = red[0];
}

__global__ __launch_bounds__(1024) void hscan_k(const int* __restrict__ hist,
                                                int* __restrict__ bcur) {
    __shared__ int s[1024];
    int t = threadIdx.x;
    s[t] = hist[t];
    __syncthreads();
    for (int off = 1; off < 1024; off <<= 1) {
        int val = (t >= off) ? s[t - off] : 0;
        __syncthreads();
        s[t] += val;
        __syncthreads();
    }
    bcur[t] = (t == 0) ? 0 : s[t - 1];
}

__global__ __launch_bounds__(256) void bbase_k(int* __restrict__ bh,
                                               const int* __restrict__ bstart, int nb) {
    __shared__ int s[256];
    int b = blockIdx.x, t = threadIdx.x;
    int v = (t < nb) ? bh[(size_t)t * 1024 + b] : 0;
    s[t] = v;
    __syncthreads();
    for (int off = 1; off < 256; off <<= 1) {
        int x = (t >= off) ? s[t - off] : 0;
        __syncthreads();
        s[t] += x;
        __syncthreads();
    }
    int excl = (t == 0) ? 0 : s[t - 1];
    if (t < nb) bh[(size_t)t * 1024 + b] = bstart[b] + excl;
}

__global__ __launch_bounds__(256) void pscatter_k(const int* __restrict__ deg,
                                                  const int* __restrict__ bh,
                                                  int* __restrict__ perm,
                                                  int* __restrict__ inv_perm, int n) {
    __shared__ int lh[1024];
    int t = threadIdx.x;
    for (int b = t; b < 1024; b += 256) lh[b] = 0;
    __syncthreads();
    int i = blockIdx.x * 256 + t;
    int b = 0, r = 0;
    if (i < n) {
        b = min(deg[i], 1023);
        r = atomicAdd(&lh[b], 1);
    }
    __syncthreads();
    if (i < n) {
        int pos = bh[(size_t)blockIdx.x * 1024 + b] + r;
        perm[pos] = i;
        inv_perm[i] = pos;
    }
}

// slot-space degree + dinv
__global__ __launch_bounds__(256) void degs_k(const int* __restrict__ deg,
                                              const int* __restrict__ perm,
                                              int* __restrict__ deg_s,
                                              float* __restrict__ dinv_s, int n) {
    int i = blockIdx.x * 256 + threadIdx.x;
    if (i < n) {
        int d = deg[perm[i]];
        deg_s[i] = d;
        dinv_s[i] = rsqrtf((float)d);
    }
}

// ---------------------------------------------------------------------------
// Device-wide exclusive scan of (deg_s[i]-1) -> rp[0..n] (slot space)
// ---------------------------------------------------------------------------
__global__ __launch_bounds__(256) void ppart_k(const int* __restrict__ deg,
                                               int* __restrict__ part, int n) {
    __shared__ int red[256];
    int t = threadIdx.x;
    int i = blockIdx.x * 256 + t;
    red[t] = (i < n) ? deg[i] - 1 : 0;
    __syncthreads();
    for (int off = 128; off; off >>= 1) {
        if (t < off) red[t] += red[t + off];
        __syncthreads();
    }
    if (t == 0) part[blockIdx.x] = red[0];
}

__global__ __launch_bounds__(256) void pscan1_k(int* __restrict__ part, int nb) {
    __shared__ int s[256];
    int t = threadIdx.x;
    s[t] = (t < nb) ? part[t] : 0;
    __syncthreads();
    for (int off = 1; off < 256; off <<= 1) {
        int v = (t >= off) ? s[t - off] : 0;
        __syncthreads();
        s[t] += v;
        __syncthreads();
    }
    if (t < nb) part[t] = (t == 0) ? 0 : s[t - 1];
}

__global__ __launch_bounds__(256) void pwrite_k(const int* __restrict__ deg,
                                                const int* __restrict__ part,
                                                int* __restrict__ rp, int n) {
    __shared__ int s[256];
    int t = threadIdx.x;
    int i = blockIdx.x * 256 + t;
    int val = (i < n) ? deg[i] - 1 : 0;
    s[t] = val;
    __syncthreads();
    for (int off = 1; off < 256; off <<= 1) {
        int v = (t >= off) ? s[t - off] : 0;
        __syncthreads();
        s[t] += v;
        __syncthreads();
    }
    int incl = s[t];
    if (i < n) rp[i] = part[blockIdx.x] + incl - val;
    if (i == n - 1) rp[n] = part[blockIdx.x] + incl;
}

// CSR scatter with renumbering; column ids stored as uint16 (slot < 65536).
__global__ __launch_bounds__(256) void scatter_k(const void* __restrict__ edges,
                                                 const int* __restrict__ flag,
                                                 const int* __restrict__ inv_perm,
                                                 const int* __restrict__ rp,
                                                 int* __restrict__ cursor,
                                                 unsigned short* __restrict__ col_s, int e) {
    int i = blockIdx.x * 256 + threadIdx.x;
    if (i < e) {
        int is32 = *flag;
        int r = inv_perm[edge_at(edges, is32, i)];
        int c = inv_perm[edge_at(edges, is32, (long long)NE + i)];
        int pos = rp[r] + atomicAdd(&cursor[r], 1);
        col_s[pos] = (unsigned short)c;
    }
}

// ---------------------------------------------------------------------------
// Hadamard: X0 = qe*obj, fp16 hi/lo split, SLOT-MAJOR panels (layer-1 input
// keeps the split: widest dynamic range).
// ---------------------------------------------------------------------------
__global__ __launch_bounds__(256) void hadamard_k(const float4* __restrict__ a,
                                                  const float4* __restrict__ b,
                                                  const int* __restrict__ perm,
                                                  _Float16* __restrict__ Xh,
                                                  _Float16* __restrict__ Xl, int n4) {
    int i = blockIdx.x * 256 + threadIdx.x;
    if (i >= n4) return;
    int slot = i >> 6;             // 64 float4 per 256-col row
    int q = i & 63;
    int v = perm[slot];
    float4 x = a[(size_t)v * 64 + q], y = b[(size_t)v * 64 + q];
    float vv[4] = { x.x * y.x, x.y * y.y, x.z * y.z, x.w * y.w };
    f16x4 hh, ll;
    #pragma unroll
    for (int j = 0; j < 4; ++j) {
        _Float16 h = (_Float16)vv[j];
        hh[j] = h;
        ll[j] = (_Float16)(vv[j] - (float)h);
    }
    int cq = q * 4;
    size_t off = ((size_t)(cq >> 5) * NN + slot) * 32 + (cq & 31);
    *(f16x4*)&Xh[off] = hh;
    *(f16x4*)&Xl[off] = ll;
}

// ---------------------------------------------------------------------------
// W convert: W[K=256][Nout] fp32 -> B3 [Nout][nseg*256] fp16.
// nseg=3: [Wh | Wl | Wh]  (pairs with A=[Ah|Ah|Al], layer 1)
// nseg=2: [Wh | Wl]       (pairs with A=[Ah|Ah],   layers 2-3)
// ---------------------------------------------------------------------------
__global__ __launch_bounds__(256) void wconv_k(const float* __restrict__ W,
                                               _Float16* __restrict__ B3,
                                               int Nout, int nseg) {
    int n = blockIdx.x;            // 0..Nout-1
    int k = threadIdx.x;           // 0..255
    float v = W[(size_t)k * Nout + n];
    _Float16 h = (_Float16)v;
    _Float16 l = (_Float16)(v - (float)h);
    size_t base = (size_t)n * (nseg * 256);
    B3[base + k]       = h;
    B3[base + 256 + k] = l;
    if (nseg == 3) B3[base + 512 + k] = h;
}

// ---------------------------------------------------------------------------
// fp16 MFMA GEMM over virtual K = NSEG*256, slot-major panels in and out.
// LDS XOR chunk-swizzle (verified r12: conflicts 2.4M -> 0).
// Epilogue writes G = dinv_s[row] * (A@W).
// ---------------------------------------------------------------------------
__device__ __forceinline__ void gload_lds16(const void* g, void* l) {
    __builtin_amdgcn_global_load_lds(
        (const __attribute__((address_space(1))) void*)g,
        (__attribute__((address_space(3))) void*)l, 16, 0, 0);
}

template <int NBX, int SW, int NSEG>
__global__ __launch_bounds__(256) void gemm_f16_k(const _Float16* __restrict__ Ah,
                                                  const _Float16* __restrict__ Al,
                                                  const _Float16* __restrict__ B3,
                                                  const float* __restrict__ dinv_s,
                                                  _Float16* __restrict__ C,
                                                  int M, int Nout) {
    __shared__ alignas(16) _Float16 sA[128 * 32];   // linear: row r at r*32, 64B rows
    __shared__ alignas(16) _Float16 sB[128 * 32];
    constexpr int LG = (SW == 32) ? 5 : 4;
    constexpr int NST = NSEG * 8;
    constexpr int BSTR = NSEG * 256;
    int mblk = (M + 127) >> 7;

    int pair, xb;
    if (NBX == 2) {
        int b = blockIdx.x;
        pair = (b >> 4) * 8 + (b & 7);     // row-panel id; pinned to XCD (b&7)
        xb   = (b >> 3) & 1;
        if (pair >= mblk) return;
    } else {
        pair = blockIdx.x;
        xb = 0;
    }

    int tid = threadIdx.x;
    int row0 = pair * 128, col0 = xb * 128;
    int wid = tid >> 6, lane = tid & 63;
    int wm = wid >> 1, wn = wid & 1;
    int fr = lane & 15;
    int kbc = lane >> 4;            // k chunk index 0..3 (8 fp16 each)

    int sr = lane >> 2;             // staging row within 16-row chunk
    int ke = (((lane & 3) ^ ((sr >> 1) & 3)) * 8);   // pre-swizzled source chunk

    f32x4 acc[4][4] = {};

    for (int s = 0; s < NST; ++s) {
        int p = s & 7;                    // A k-panel index
        const _Float16* Asrc = Ah;
        if constexpr (NSEG == 3) {
            if ((s >> 3) == 2) Asrc = Al;
        }

        __syncthreads();                  // LDS reuse: prior reads done
        #pragma unroll
        for (int c = 0; c < 2; ++c) {
            int ch = wid * 2 + c;         // 0..7
            int r = ch * 16 + sr;
            int arow = row0 + r;
            if (arow < M)
                gload_lds16(&Asrc[((size_t)p * M + arow) * 32 + ke], &sA[ch * 512]);
            gload_lds16(&B3[(size_t)(col0 + r) * BSTR + s * 32 + ke], &sB[ch * 512]);
        }
        __syncthreads();                  // drains vmcnt (global_load_lds) too

        f16x8 af[4];
        #pragma unroll
        for (int f = 0; f < 4; ++f) {
            int rr = wm * 64 + f * 16 + fr;
            af[f] = *(const f16x8*)&sA[rr * 32 + ((kbc ^ ((rr >> 1) & 3)) * 8)];
        }
        #pragma unroll
        for (int g = 0; g < 4; ++g) {
            int cc = wn * 64 + g * 16 + fr;
            f16x8 bf_ = *(const f16x8*)&sB[cc * 32 + ((kbc ^ ((cc >> 1) & 3)) * 8)];
            #pragma unroll
            for (int f = 0; f < 4; ++f)
                acc[f][g] = __builtin_amdgcn_mfma_f32_16x16x32_f16(af[f], bf_, acc[f][g], 0, 0, 0);
        }
    }

    int rsub = (lane >> 4) * 4;
    float dsc[4][4];
    #pragma unroll
    for (int f = 0; f < 4; ++f)
        #pragma unroll
        for (int r = 0; r < 4; ++r) {
            int row = row0 + wm * 64 + f * 16 + rsub + r;
            dsc[f][r] = (row < M) ? dinv_s[row] : 0.0f;
        }
    #pragma unroll
    for (int f = 0; f < 4; ++f) {
        #pragma unroll
        for (int g = 0; g < 4; ++g) {
            int col = col0 + wn * 64 + g * 16 + fr;
            #pragma unroll
            for (int r = 0; r < 4; ++r) {
                int row = row0 + wm * 64 + f * 16 + rsub + r;
                if (row < M)
                    C[((size_t)(col >> LG) * M + row) * SW + (col & (SW - 1))] =
                        (_Float16)(acc[f][g][r] * dsc[f][r]);
            }
        }
    }
}

// ---------------------------------------------------------------------------
// XCD-sliced aggregation v8: slot-space, uint16 cs, single-fp16 output
// (no lo-split) for MODE 0. MODE 1: fp32 scatter to orig rows.
// ---------------------------------------------------------------------------
template <int D, int MODE>
__global__ __launch_bounds__(256) void aggregate_slice_k(const _Float16* __restrict__ G,
                                                         const float* __restrict__ bias,
                                                         const float* __restrict__ dinv_s,
                                                         const int* __restrict__ rp,
                                                         const unsigned short* __restrict__ cs,
                                                         const int* __restrict__ perm,
                                                         _Float16* __restrict__ Yh,
                                                         float* __restrict__ Yf, int n) {
    constexpr int SLICE = (D == 256) ? 32 : 16;   // panel width
    constexpr int LPN = SLICE / 8;                // lanes per node (f16x8 each)
    constexpr int NPB = 256 / LPN;                // nodes per block

    int bid = blockIdx.x;
    int s = bid & 7;
    int slot = (bid >> 3) * NPB + threadIdx.x / LPN;
    if (slot >= n) return;
    int sub = threadIdx.x % LPN;
    int co = sub * 8;                             // within-panel col offset
    int col = s * SLICE + co;                     // global col (bias / out)

    const _Float16* Gs = G + (size_t)s * n * SLICE;   // this slice's panel

    float acc[8];
    {
        f16x8 t0 = *(const f16x8*)&Gs[(size_t)slot * SLICE + co];
        #pragma unroll
        for (int i = 0; i < 8; ++i) acc[i] = (float)t0[i];
    }

    int beg = rp[slot], end = rp[slot + 1];
    int j = beg;
    for (; j + 8 <= end; j += 8) {
        int cc[8];
        #pragma unroll
        for (int u = 0; u < 8; ++u) cc[u] = cs[j + u];
        f16x8 hv[8];
        #pragma unroll
        for (int u = 0; u < 8; ++u)
            hv[u] = *(const f16x8*)&Gs[(size_t)cc[u] * SLICE + co];
        #pragma unroll
        for (int u = 0; u < 8; ++u)
            #pragma unroll
            for (int i = 0; i < 8; ++i)
                acc[i] += (float)hv[u][i];
    }
    for (; j < end; ++j) {
        int c = cs[j];
        f16x8 a = *(const f16x8*)&Gs[(size_t)c * SLICE + co];
        #pragma unroll
        for (int i = 0; i < 8; ++i) acc[i] += (float)a[i];
    }

    float dv = dinv_s[slot];
    float4 b0 = *(const float4*)&bias[col];
    float4 b1 = *(const float4*)&bias[col + 4];
    float bb[8] = { b0.x, b0.y, b0.z, b0.w, b1.x, b1.y, b1.z, b1.w };

    if constexpr (MODE == 0) {
        f16x8 hh;
        #pragma unroll
        for (int i = 0; i < 8; ++i)
            hh[i] = (_Float16)fmaxf(dv * acc[i] + bb[i], 0.0f);
        size_t off = ((size_t)s * n + slot) * SLICE + co;   // slot-major out
        *(f16x8*)&Yh[off] = hh;
    } else {
        int v = perm[slot];                                 // orig node id
        float o[8];
        #pragma unroll
        for (int i = 0; i < 8; ++i) o[i] = dv * acc[i] + bb[i];
        *(float4*)&Yf[(size_t)v * D + col]     = make_float4(o[0], o[1], o[2], o[3]);
        *(float4*)&Yf[(size_t)v * D + col + 4] = make_float4(o[4], o[5], o[6], o[7]);
    }
}

// ---------------------------------------------------------------------------
extern "C" void kernel_launch(void* const* d_in, const int* in_sizes, int n_in,
                              void* d_out, int out_size, void* d_ws, size_t ws_size,
                              hipStream_t stream) {
    const float* qe  = (const float*)d_in[0];
    const float* obj = (const float*)d_in[1];
    const void*  edges = d_in[2];
    const float* W1 = (const float*)d_in[3];
    const float* b1 = (const float*)d_in[4];
    const float* W2 = (const float*)d_in[5];
    const float* b2 = (const float*)d_in[6];
    const float* W3 = (const float*)d_in[7];
    const float* b3 = (const float*)d_in[8];
    float* out = (float*)d_out;

    char* p = (char*)d_ws;
    _Float16* Xh   = (_Float16*)p; p += (size_t)NN * 256 * 2;   // 25.6 MB (slot-major)
    _Float16* Xl   = (_Float16*)p; p += (size_t)NN * 256 * 2;   // 25.6 MB (slot-major)
    _Float16* H    = (_Float16*)p; p += (size_t)NN * 256 * 2;   // 25.6 MB (slot-major G)
    _Float16* B3   = (_Float16*)p; p += (size_t)256 * 768 * 2;  // 0.4 MB
    int*   deg     = (int*)p;   p += (size_t)NN * 4;
    int*   deg_s   = (int*)p;   p += (size_t)NN * 4;
    float* dinv_s  = (float*)p; p += (size_t)NN * 4;
    int*   rp      = (int*)p;   p += (size_t)(NN + 1) * 4;
    int*   cursor  = (int*)p;   p += (size_t)NN * 4;
    unsigned short* col_s = (unsigned short*)p; p += (size_t)NE * 2;
    int*   bh      = (int*)p;   p += (size_t)NBLK * 1024 * 4;   // 0.8 MB
    int*   tot     = (int*)p;   p += 1024 * 4;
    int*   bstart  = (int*)p;   p += 1024 * 4;
    int*   part    = (int*)p;   p += NBLK * 4;
    int*   perm    = (int*)p;   p += (size_t)NN * 4;
    int*   inv_perm= (int*)p;   p += (size_t)NN * 4;
    int*   flag    = (int*)p;   p += 4;

    zero_flag_k<<<1, 64, 0, stream>>>(flag);
    detect_k<<<4, 256, 0, stream>>>((const int*)edges, flag);
    init_k<<<(NN + 255) / 256, 256, 0, stream>>>(deg, cursor, NN);
    count_k<<<(NE + 255) / 256, 256, 0, stream>>>(edges, flag, deg, NE);
    // degree-sorted renumbering
    bh_k<<<NBLK, 256, 0, stream>>>(deg, bh, NN);
    btot_k<<<1024, 256, 0, stream>>>(bh, tot, NBLK);
    hscan_k<<<1, 1024, 0, stream>>>(tot, bstart);
    bbase_k<<<1024, 256, 0, stream>>>(bh, bstart, NBLK);
    pscatter_k<<<NBLK, 256, 0, stream>>>(deg, bh, perm, inv_perm, NN);
    degs_k<<<NBLK, 256, 0, stream>>>(deg, perm, deg_s, dinv_s, NN);
    // rp over slot-space degrees
    ppart_k<<<NBLK, 256, 0, stream>>>(deg_s, part, NN);
    pscan1_k<<<1, 256, 0, stream>>>(part, NBLK);
    pwrite_k<<<NBLK, 256, 0, stream>>>(deg_s, part, rp, NN);
    // translated CSR (uint16 columns)
    scatter_k<<<(NE + 255) / 256, 256, 0, stream>>>(edges, flag, inv_perm, rp, cursor,
                                                    col_s, NE);
    // slot-major X0 (hi/lo split kept for layer 1)
    hadamard_k<<<(NN * 64 + 255) / 256, 256, 0, stream>>>(
        (const float4*)qe, (const float4*)obj, perm, Xh, Xl, NN * 64);

    int mblk = (NN + 127) / 128;                 // 391
    int gemmBigGrid = ((mblk + 7) / 8) * 16;     // 800 (pair-swizzled, 2 col blocks)
    int agg256Grid = ((NN + 63) / 64) * 8;       // 6256  (64 nodes/block, 4 lanes/node)
    int agg128Grid = ((NN + 127) / 128) * 8;     // 3128  (128 nodes/block, 2 lanes/node)

    // Layer 1 (split input, K=768)
    wconv_k<<<256, 256, 0, stream>>>(W1, B3, 256, 3);
    gemm_f16_k<2, 32, 3><<<gemmBigGrid, 256, 0, stream>>>(Xh, Xl, B3, dinv_s, H, NN, 256);
    aggregate_slice_k<256, 0><<<agg256Grid, 256, 0, stream>>>(H, b1, dinv_s, rp, col_s, perm,
                                                              Xh, nullptr, NN);
    // Layer 2 (single-fp16 input, K=512)
    wconv_k<<<256, 256, 0, stream>>>(W2, B3, 256, 2);
    gemm_f16_k<2, 32, 2><<<gemmBigGrid, 256, 0, stream>>>(Xh, nullptr, B3, dinv_s, H, NN, 256);
    aggregate_slice_k<256, 0><<<agg256Grid, 256, 0, stream>>>(H, b2, dinv_s, rp, col_s, perm,
                                                              Xh, nullptr, NN);
    // Layer 3 (single-fp16 input, K=512)
    wconv_k<<<128, 256, 0, stream>>>(W3, B3, 128, 2);
    gemm_f16_k<1, 16, 2><<<mblk, 256, 0, stream>>>(Xh, nullptr, B3, dinv_s, H, NN, 128);
    aggregate_slice_k<128, 1><<<agg128Grid, 256, 0, stream>>>(H, b3, dinv_s, rp, col_s, perm,
                                                              nullptr, out, NN);
}

// Round 14
// 342.739 us; speedup vs baseline: 2.3085x; 1.0401x over previous
//
#include <hip/hip_runtime.h>
#include <cstdint>
#include <cstddef>

#define NN 50000
#define NE 800000
#define NBLK ((NN + 255) / 256)   // 196 node-chunks

typedef _Float16 f16x8 __attribute__((ext_vector_type(8)));
typedef _Float16 f16x4 __attribute__((ext_vector_type(4)));
typedef float f32x4 __attribute__((ext_vector_type(4)));

// ---------------------------------------------------------------------------
// Edge-index dtype robustness (int64 vs int32 canonicalization)
// ---------------------------------------------------------------------------
__device__ __forceinline__ int edge_at(const void* e, int is32, long long i) {
    return is32 ? ((const int*)e)[i] : (int)((const long long*)e)[i];
}

__global__ __launch_bounds__(64) void zero_flag_k(int* flag) {
    if (threadIdx.x == 0) *flag = 0;
}

__global__ __launch_bounds__(256) void detect_k(const int* __restrict__ w, int* __restrict__ flag) {
    int i = blockIdx.x * 256 + threadIdx.x;   // 0..1023
    if (i < 1024 && w[2 * i + 1] != 0) atomicOr(flag, 1);
}

// ---------------------------------------------------------------------------
// Degree count (original node ids)
// ---------------------------------------------------------------------------
__global__ __launch_bounds__(256) void init_k(int* __restrict__ deg, int* __restrict__ cursor, int n) {
    int i = blockIdx.x * 256 + threadIdx.x;
    if (i < n) { deg[i] = 1; cursor[i] = 0; }   // self-loop
}

__global__ __launch_bounds__(256) void count_k(const void* __restrict__ edges,
                                               const int* __restrict__ flag,
                                               int* __restrict__ deg, int e) {
    int i = blockIdx.x * 256 + threadIdx.x;
    if (i < e) {
        int is32 = *flag;
        atomicAdd(&deg[edge_at(edges, is32, i)], 1);
    }
}

// ---------------------------------------------------------------------------
// Degree-sorted node permutation, contention-free 3-phase counting sort.
// ---------------------------------------------------------------------------
__global__ __launch_bounds__(256) void bh_k(const int* __restrict__ deg,
                                            int* __restrict__ bh, int n) {
    __shared__ int lh[1024];
    int t = threadIdx.x;
    for (int b = t; b < 1024; b += 256) lh[b] = 0;
    __syncthreads();
    int i = blockIdx.x * 256 + t;
    if (i < n) atomicAdd(&lh[min(deg[i], 1023)], 1);
    __syncthreads();
    for (int b = t; b < 1024; b += 256) bh[(size_t)blockIdx.x * 1024 + b] = lh[b];
}

__global__ __launch_bounds__(256) void btot_k(const int* __restrict__ bh,
                                              int* __restrict__ tot, int nb) {
    __shared__ int red[256];
    int b = blockIdx.x, t = threadIdx.x;
    int s = 0;
    for (int blk = t; blk < nb; blk += 256) s += bh[(size_t)blk * 1024 + b];
    red[t] = s;
    __syncthreads();
    for (int off = 128; off; off >>= 1) {
        if (t < off) red[t] += red[t + off];
        __syncthreads();
    }
    if (t == 0) tot[b] = red[0];
}

__global__ __launch_bounds__(1024) void hscan_k(const int* __restrict__ hist,
                                                int* __restrict__ bcur) {
    __shared__ int s[1024];
    int t = threadIdx.x;
    s[t] = hist[t];
    __syncthreads();
    for (int off = 1; off < 1024; off <<= 1) {
        int val = (t >= off) ? s[t - off] : 0;
        __syncthreads();
        s[t] += val;
        __syncthreads();
    }
    bcur[t] = (t == 0) ? 0 : s[t - 1];
}

__global__ __launch_bounds__(256) void bbase_k(int* __restrict__ bh,
                                               const int* __restrict__ bstart, int nb) {
    __shared__ int s[256];
    int b = blockIdx.x, t = threadIdx.x;
    int v = (t < nb) ? bh[(size_t)t * 1024 + b] : 0;
    s[t] = v;
    __syncthreads();
    for (int off = 1; off < 256; off <<= 1) {
        int x = (t >= off) ? s[t - off] : 0;
        __syncthreads();
        s[t] += x;
        __syncthreads();
    }
    int excl = (t == 0) ? 0 : s[t - 1];
    if (t < nb) bh[(size_t)t * 1024 + b] = bstart[b] + excl;
}

__global__ __launch_bounds__(256) void pscatter_k(const int* __restrict__ deg,
                                                  const int* __restrict__ bh,
                                                  int* __restrict__ perm,
                                                  int* __restrict__ inv_perm, int n) {
    __shared__ int lh[1024];
    int t = threadIdx.x;
    for (int b = t; b < 1024; b += 256) lh[b] = 0;
    __syncthreads();
    int i = blockIdx.x * 256 + t;
    int b = 0, r = 0;
    if (i < n) {
        b = min(deg[i], 1023);
        r = atomicAdd(&lh[b], 1);
    }
    __syncthreads();
    if (i < n) {
        int pos = bh[(size_t)blockIdx.x * 1024 + b] + r;
        perm[pos] = i;
        inv_perm[i] = pos;
    }
}

// slot-space degree + dinv
__global__ __launch_bounds__(256) void degs_k(const int* __restrict__ deg,
                                              const int* __restrict__ perm,
                                              int* __restrict__ deg_s,
                                              float* __restrict__ dinv_s, int n) {
    int i = blockIdx.x * 256 + threadIdx.x;
    if (i < n) {
        int d = deg[perm[i]];
        deg_s[i] = d;
        dinv_s[i] = rsqrtf((float)d);
    }
}

// ---------------------------------------------------------------------------
// Device-wide exclusive scan of (deg_s[i]-1) -> rp[0..n] (slot space)
// ---------------------------------------------------------------------------
__global__ __launch_bounds__(256) void ppart_k(const int* __restrict__ deg,
                                               int* __restrict__ part, int n) {
    __shared__ int red[256];
    int t = threadIdx.x;
    int i = blockIdx.x * 256 + t;
    red[t] = (i < n) ? deg[i] - 1 : 0;
    __syncthreads();
    for (int off = 128; off; off >>= 1) {
        if (t < off) red[t] += red[t + off];
        __syncthreads();
    }
    if (t == 0) part[blockIdx.x] = red[0];
}

__global__ __launch_bounds__(256) void pscan1_k(int* __restrict__ part, int nb) {
    __shared__ int s[256];
    int t = threadIdx.x;
    s[t] = (t < nb) ? part[t] : 0;
    __syncthreads();
    for (int off = 1; off < 256; off <<= 1) {
        int v = (t >= off) ? s[t - off] : 0;
        __syncthreads();
        s[t] += v;
        __syncthreads();
    }
    if (t < nb) part[t] = (t == 0) ? 0 : s[t - 1];
}

__global__ __launch_bounds__(256) void pwrite_k(const int* __restrict__ deg,
                                                const int* __restrict__ part,
                                                int* __restrict__ rp, int n) {
    __shared__ int s[256];
    int t = threadIdx.x;
    int i = blockIdx.x * 256 + t;
    int val = (i < n) ? deg[i] - 1 : 0;
    s[t] = val;
    __syncthreads();
    for (int off = 1; off < 256; off <<= 1) {
        int v = (t >= off) ? s[t - off] : 0;
        __syncthreads();
        s[t] += v;
        __syncthreads();
    }
    int incl = s[t];
    if (i < n) rp[i] = part[blockIdx.x] + incl - val;
    if (i == n - 1) rp[n] = part[blockIdx.x] + incl;
}

// CSR scatter with renumbering; column ids stored as uint16 (slot < 65536).
__global__ __launch_bounds__(256) void scatter_k(const void* __restrict__ edges,
                                                 const int* __restrict__ flag,
                                                 const int* __restrict__ inv_perm,
                                                 const int* __restrict__ rp,
                                                 int* __restrict__ cursor,
                                                 unsigned short* __restrict__ col_s, int e) {
    int i = blockIdx.x * 256 + threadIdx.x;
    if (i < e) {
        int is32 = *flag;
        int r = inv_perm[edge_at(edges, is32, i)];
        int c = inv_perm[edge_at(edges, is32, (long long)NE + i)];
        int pos = rp[r] + atomicAdd(&cursor[r], 1);
        col_s[pos] = (unsigned short)c;
    }
}

// ---------------------------------------------------------------------------
// Hadamard: X0 = qe*obj, single fp16 (lo-split dropped: r13 showed absmax is
// dominated by fp16 G storage, not input rounding), SLOT-MAJOR panels.
// ---------------------------------------------------------------------------
__global__ __launch_bounds__(256) void hadamard_k(const float4* __restrict__ a,
                                                  const float4* __restrict__ b,
                                                  const int* __restrict__ perm,
                                                  _Float16* __restrict__ Xh, int n4) {
    int i = blockIdx.x * 256 + threadIdx.x;
    if (i >= n4) return;
    int slot = i >> 6;             // 64 float4 per 256-col row
    int q = i & 63;
    int v = perm[slot];
    float4 x = a[(size_t)v * 64 + q], y = b[(size_t)v * 64 + q];
    f16x4 hh;
    hh[0] = (_Float16)(x.x * y.x);
    hh[1] = (_Float16)(x.y * y.y);
    hh[2] = (_Float16)(x.z * y.z);
    hh[3] = (_Float16)(x.w * y.w);
    int cq = q * 4;
    size_t off = ((size_t)(cq >> 5) * NN + slot) * 32 + (cq & 31);
    *(f16x4*)&Xh[off] = hh;
}

// ---------------------------------------------------------------------------
// W convert: W[K=256][Nout] fp32 -> B3 [Nout][512] fp16, layout [Wh | Wl]
// (pairs with A=[Ah|Ah]: A@Wh + A@Wl keeps W at full fp32 precision).
// ---------------------------------------------------------------------------
__global__ __launch_bounds__(256) void wconv_k(const float* __restrict__ W,
                                               _Float16* __restrict__ B3, int Nout) {
    int n = blockIdx.x;            // 0..Nout-1
    int k = threadIdx.x;           // 0..255
    float v = W[(size_t)k * Nout + n];
    _Float16 h = (_Float16)v;
    B3[(size_t)n * 512 + k]       = h;
    B3[(size_t)n * 512 + 256 + k] = (_Float16)(v - (float)h);
}

// ---------------------------------------------------------------------------
// fp16 MFMA GEMM over virtual K=512, slot-major panels in and out.
// Double-buffered LDS (T3-minimal): STAGE(next) issued before compute(cur),
// ONE __syncthreads per step -> stage latency overlaps MFMA+ds_read.
// LDS XOR chunk-swizzle retained (r12: conflicts 2.4M -> 0).
// Epilogue writes G = dinv_s[row] * (A@W).
// ---------------------------------------------------------------------------
__device__ __forceinline__ void gload_lds16(const void* g, void* l) {
    __builtin_amdgcn_global_load_lds(
        (const __attribute__((address_space(1))) void*)g,
        (__attribute__((address_space(3))) void*)l, 16, 0, 0);
}

template <int NBX, int SW>
__global__ __launch_bounds__(256) void gemm_f16_k(const _Float16* __restrict__ Ah,
                                                  const _Float16* __restrict__ B3,
                                                  const float* __restrict__ dinv_s,
                                                  _Float16* __restrict__ C,
                                                  int M, int Nout) {
    __shared__ alignas(16) _Float16 sA[2][128 * 32];
    __shared__ alignas(16) _Float16 sB[2][128 * 32];
    constexpr int LG = (SW == 32) ? 5 : 4;
    constexpr int NST = 16;           // K = 512 / 32
    int mblk = (M + 127) >> 7;

    int pair, xb;
    if (NBX == 2) {
        int b = blockIdx.x;
        pair = (b >> 4) * 8 + (b & 7);     // row-panel id; pinned to XCD (b&7)
        xb   = (b >> 3) & 1;
        if (pair >= mblk) return;
    } else {
        pair = blockIdx.x;
        xb = 0;
    }

    int tid = threadIdx.x;
    int row0 = pair * 128, col0 = xb * 128;
    int wid = tid >> 6, lane = tid & 63;
    int wm = wid >> 1, wn = wid & 1;
    int fr = lane & 15;
    int kbc = lane >> 4;            // k chunk index 0..3 (8 fp16 each)

    int sr = lane >> 2;             // staging row within 16-row chunk
    int ke = (((lane & 3) ^ ((sr >> 1) & 3)) * 8);   // pre-swizzled source chunk

    f32x4 acc[4][4] = {};

    // staging for step s into buffer bsel
    auto STAGE = [&](int bsel, int s) {
        int p = s & 7;                    // A k-panel index (s<8: Wh half, s>=8: Wl half)
        #pragma unroll
        for (int c = 0; c < 2; ++c) {
            int ch = wid * 2 + c;         // 0..7
            int r = ch * 16 + sr;
            int arow = row0 + r;
            if (arow < M)
                gload_lds16(&Ah[((size_t)p * M + arow) * 32 + ke], &sA[bsel][ch * 512]);
            gload_lds16(&B3[(size_t)(col0 + r) * 512 + s * 32 + ke], &sB[bsel][ch * 512]);
        }
    };

    STAGE(0, 0);
    __syncthreads();                      // drain prologue stage
    int cur = 0;

    for (int s = 0; s < NST; ++s) {
        if (s + 1 < NST) STAGE(cur ^ 1, s + 1);   // overlaps with compute below

        f16x8 af[4];
        #pragma unroll
        for (int f = 0; f < 4; ++f) {
            int rr = wm * 64 + f * 16 + fr;
            af[f] = *(const f16x8*)&sA[cur][rr * 32 + ((kbc ^ ((rr >> 1) & 3)) * 8)];
        }
        #pragma unroll
        for (int g = 0; g < 4; ++g) {
            int cc = wn * 64 + g * 16 + fr;
            f16x8 bf_ = *(const f16x8*)&sB[cur][cc * 32 + ((kbc ^ ((cc >> 1) & 3)) * 8)];
            #pragma unroll
            for (int f = 0; f < 4; ++f)
                acc[f][g] = __builtin_amdgcn_mfma_f32_16x16x32_f16(af[f], bf_, acc[f][g], 0, 0, 0);
        }

        __syncthreads();                  // drains next-stage vmcnt + our ds_reads
        cur ^= 1;
    }

    int rsub = (lane >> 4) * 4;
    float dsc[4][4];
    #pragma unroll
    for (int f = 0; f < 4; ++f)
        #pragma unroll
        for (int r = 0; r < 4; ++r) {
            int row = row0 + wm * 64 + f * 16 + rsub + r;
            dsc[f][r] = (row < M) ? dinv_s[row] : 0.0f;
        }
    #pragma unroll
    for (int f = 0; f < 4; ++f) {
        #pragma unroll
        for (int g = 0; g < 4; ++g) {
            int col = col0 + wn * 64 + g * 16 + fr;
            #pragma unroll
            for (int r = 0; r < 4; ++r) {
                int row = row0 + wm * 64 + f * 16 + rsub + r;
                if (row < M)
                    C[((size_t)(col >> LG) * M + row) * SW + (col & (SW - 1))] =
                        (_Float16)(acc[f][g][r] * dsc[f][r]);
            }
        }
    }
}

// ---------------------------------------------------------------------------
// XCD-sliced aggregation: slot-space, uint16 cs, single-fp16 output for
// MODE 0. MODE 1: fp32 scatter to orig rows.
// ---------------------------------------------------------------------------
template <int D, int MODE>
__global__ __launch_bounds__(256) void aggregate_slice_k(const _Float16* __restrict__ G,
                                                         const float* __restrict__ bias,
                                                         const float* __restrict__ dinv_s,
                                                         const int* __restrict__ rp,
                                                         const unsigned short* __restrict__ cs,
                                                         const int* __restrict__ perm,
                                                         _Float16* __restrict__ Yh,
                                                         float* __restrict__ Yf, int n) {
    constexpr int SLICE = (D == 256) ? 32 : 16;   // panel width
    constexpr int LPN = SLICE / 8;                // lanes per node (f16x8 each)
    constexpr int NPB = 256 / LPN;                // nodes per block

    int bid = blockIdx.x;
    int s = bid & 7;
    int slot = (bid >> 3) * NPB + threadIdx.x / LPN;
    if (slot >= n) return;
    int sub = threadIdx.x % LPN;
    int co = sub * 8;                             // within-panel col offset
    int col = s * SLICE + co;                     // global col (bias / out)

    const _Float16* Gs = G + (size_t)s * n * SLICE;   // this slice's panel

    float acc[8];
    {
        f16x8 t0 = *(const f16x8*)&Gs[(size_t)slot * SLICE + co];
        #pragma unroll
        for (int i = 0; i < 8; ++i) acc[i] = (float)t0[i];
    }

    int beg = rp[slot], end = rp[slot + 1];
    int j = beg;
    for (; j + 8 <= end; j += 8) {
        int cc[8];
        #pragma unroll
        for (int u = 0; u < 8; ++u) cc[u] = cs[j + u];
        f16x8 hv[8];
        #pragma unroll
        for (int u = 0; u < 8; ++u)
            hv[u] = *(const f16x8*)&Gs[(size_t)cc[u] * SLICE + co];
        #pragma unroll
        for (int u = 0; u < 8; ++u)
            #pragma unroll
            for (int i = 0; i < 8; ++i)
                acc[i] += (float)hv[u][i];
    }
    for (; j < end; ++j) {
        int c = cs[j];
        f16x8 a = *(const f16x8*)&Gs[(size_t)c * SLICE + co];
        #pragma unroll
        for (int i = 0; i < 8; ++i) acc[i] += (float)a[i];
    }

    float dv = dinv_s[slot];
    float4 b0 = *(const float4*)&bias[col];
    float4 b1 = *(const float4*)&bias[col + 4];
    float bb[8] = { b0.x, b0.y, b0.z, b0.w, b1.x, b1.y, b1.z, b1.w };

    if constexpr (MODE == 0) {
        f16x8 hh;
        #pragma unroll
        for (int i = 0; i < 8; ++i)
            hh[i] = (_Float16)fmaxf(dv * acc[i] + bb[i], 0.0f);
        size_t off = ((size_t)s * n + slot) * SLICE + co;   // slot-major out
        *(f16x8*)&Yh[off] = hh;
    } else {
        int v = perm[slot];                                 // orig node id
        float o[8];
        #pragma unroll
        for (int i = 0; i < 8; ++i) o[i] = dv * acc[i] + bb[i];
        *(float4*)&Yf[(size_t)v * D + col]     = make_float4(o[0], o[1], o[2], o[3]);
        *(float4*)&Yf[(size_t)v * D + col + 4] = make_float4(o[4], o[5], o[6], o[7]);
    }
}

// ---------------------------------------------------------------------------
extern "C" void kernel_launch(void* const* d_in, const int* in_sizes, int n_in,
                              void* d_out, int out_size, void* d_ws, size_t ws_size,
                              hipStream_t stream) {
    const float* qe  = (const float*)d_in[0];
    const float* obj = (const float*)d_in[1];
    const void*  edges = d_in[2];
    const float* W1 = (const float*)d_in[3];
    const float* b1 = (const float*)d_in[4];
    const float* W2 = (const float*)d_in[5];
    const float* b2 = (const float*)d_in[6];
    const float* W3 = (const float*)d_in[7];
    const float* b3 = (const float*)d_in[8];
    float* out = (float*)d_out;

    char* p = (char*)d_ws;
    _Float16* Xh   = (_Float16*)p; p += (size_t)NN * 256 * 2;   // 25.6 MB (slot-major)
    _Float16* H    = (_Float16*)p; p += (size_t)NN * 256 * 2;   // 25.6 MB (slot-major G)
    _Float16* B3   = (_Float16*)p; p += (size_t)256 * 512 * 2;  // 0.26 MB
    int*   deg     = (int*)p;   p += (size_t)NN * 4;
    int*   deg_s   = (int*)p;   p += (size_t)NN * 4;
    float* dinv_s  = (float*)p; p += (size_t)NN * 4;
    int*   rp      = (int*)p;   p += (size_t)(NN + 1) * 4;
    int*   cursor  = (int*)p;   p += (size_t)NN * 4;
    unsigned short* col_s = (unsigned short*)p; p += (size_t)NE * 2;
    int*   bh      = (int*)p;   p += (size_t)NBLK * 1024 * 4;   // 0.8 MB
    int*   tot     = (int*)p;   p += 1024 * 4;
    int*   bstart  = (int*)p;   p += 1024 * 4;
    int*   part    = (int*)p;   p += NBLK * 4;
    int*   perm    = (int*)p;   p += (size_t)NN * 4;
    int*   inv_perm= (int*)p;   p += (size_t)NN * 4;
    int*   flag    = (int*)p;   p += 4;

    zero_flag_k<<<1, 64, 0, stream>>>(flag);
    detect_k<<<4, 256, 0, stream>>>((const int*)edges, flag);
    init_k<<<(NN + 255) / 256, 256, 0, stream>>>(deg, cursor, NN);
    count_k<<<(NE + 255) / 256, 256, 0, stream>>>(edges, flag, deg, NE);
    // degree-sorted renumbering
    bh_k<<<NBLK, 256, 0, stream>>>(deg, bh, NN);
    btot_k<<<1024, 256, 0, stream>>>(bh, tot, NBLK);
    hscan_k<<<1, 1024, 0, stream>>>(tot, bstart);
    bbase_k<<<1024, 256, 0, stream>>>(bh, bstart, NBLK);
    pscatter_k<<<NBLK, 256, 0, stream>>>(deg, bh, perm, inv_perm, NN);
    degs_k<<<NBLK, 256, 0, stream>>>(deg, perm, deg_s, dinv_s, NN);
    // rp over slot-space degrees
    ppart_k<<<NBLK, 256, 0, stream>>>(deg_s, part, NN);
    pscan1_k<<<1, 256, 0, stream>>>(part, NBLK);
    pwrite_k<<<NBLK, 256, 0, stream>>>(deg_s, part, rp, NN);
    // translated CSR (uint16 columns)
    scatter_k<<<(NE + 255) / 256, 256, 0, stream>>>(edges, flag, inv_perm, rp, cursor,
                                                    col_s, NE);
    // slot-major X0 (single fp16)
    hadamard_k<<<(NN * 64 + 255) / 256, 256, 0, stream>>>(
        (const float4*)qe, (const float4*)obj, perm, Xh, NN * 64);

    int mblk = (NN + 127) / 128;                 // 391
    int gemmBigGrid = ((mblk + 7) / 8) * 16;     // 800 (pair-swizzled, 2 col blocks)
    int agg256Grid = ((NN + 63) / 64) * 8;       // 6256  (64 nodes/block, 4 lanes/node)
    int agg128Grid = ((NN + 127) / 128) * 8;     // 3128  (128 nodes/block, 2 lanes/node)

    // Layer 1
    wconv_k<<<256, 256, 0, stream>>>(W1, B3, 256);
    gemm_f16_k<2, 32><<<gemmBigGrid, 256, 0, stream>>>(Xh, B3, dinv_s, H, NN, 256);
    aggregate_slice_k<256, 0><<<agg256Grid, 256, 0, stream>>>(H, b1, dinv_s, rp, col_s, perm,
                                                              Xh, nullptr, NN);
    // Layer 2
    wconv_k<<<256, 256, 0, stream>>>(W2, B3, 256);
    gemm_f16_k<2, 32><<<gemmBigGrid, 256, 0, stream>>>(Xh, B3, dinv_s, H, NN, 256);
    aggregate_slice_k<256, 0><<<agg256Grid, 256, 0, stream>>>(H, b2, dinv_s, rp, col_s, perm,
                                                              Xh, nullptr, NN);
    // Layer 3
    wconv_k<<<128, 256, 0, stream>>>(W3, B3, 128);
    gemm_f16_k<1, 16><<<mblk, 256, 0, stream>>>(Xh, B3, dinv_s, H, NN, 128);
    aggregate_slice_k<128, 1><<<agg128Grid, 256, 0, stream>>>(H, b3, dinv_s, rp, col_s, perm,
                                                              nullptr, out, NN);
}